// Round 1
// baseline (412.902 us; speedup 1.0000x reference)
//
#include <hip/hip_runtime.h>
#include <stdint.h>

// MultiHeadSelfAttention: B=2 T=2048 C=1024 H=16 D=64, fp32 in/out.
// Strategy: split-precision bf16x3 MFMA (x = hi+lo bf16; a*b ~= ah*bh + ah*bl + al*bh),
// fp32 accumulate. All operands pre-packed as u32 = (hi16<<16)|lo16 so GEMM/attn
// tiles stage via global_load_lds(16B) with pre-swizzled source addresses
// (linear LDS + XOR-swizzled reads -> no 128B-row bank conflicts).
// Pipeline: pack(x) ; transpose-pack(w_qkv) ; transpose-pack(w_proj) ;
//           qkv GEMM (writes Q,K packed [bh][t][d], V packed-transposed [bh][d][t]) ;
//           flash attention (causal, online softmax) -> ctx packed ;
//           proj GEMM -> fp32 out.
// Workspace: 80 MB (xp/ctx aliased 16MB | wqt 12 | wpt 4 | qp 16 | kp 16 | vt 16).

#define B_  2
#define T_  2048
#define C_  1024
#define NH  16
#define HD  64
#define BH_ (B_*NH)   // 32
#define M_  (B_*T_)   // 4096

typedef __attribute__((ext_vector_type(8))) short short8;
typedef __attribute__((ext_vector_type(4))) float f32x4;
typedef __attribute__((ext_vector_type(4))) uint32_t u32x4;

struct frag2 { short8 hi, lo; };

typedef const __attribute__((address_space(1))) void* gas_ptr;
typedef __attribute__((address_space(3))) void* las_ptr;

__device__ __forceinline__ void gload_lds16(const void* g, void* l) {
  __builtin_amdgcn_global_load_lds((gas_ptr)g, (las_ptr)l, 16, 0, 0);
}

// fp32 -> packed (bf16 hi in high 16 bits [truncated], bf16 lo in low 16 [RNE])
__device__ __forceinline__ uint32_t packsplit(float x) {
  uint32_t u = __float_as_uint(x);
  uint32_t hib = u & 0xffff0000u;
  float r = x - __uint_as_float(hib);
  uint32_t v = __float_as_uint(r);
  uint32_t lo = (v + 0x7fffu + ((v >> 16) & 1u)) >> 16;
  return hib | lo;
}

// 8 packed u32 -> hi-frag and lo-frag (short8 of bf16 bits) via v_perm
__device__ __forceinline__ frag2 extract2(u32x4 a, u32x4 b) {
  union U { u32x4 u; short8 s; };
  U H, L;
  H.u[0] = __builtin_amdgcn_perm(a[1], a[0], 0x07060302u);
  H.u[1] = __builtin_amdgcn_perm(a[3], a[2], 0x07060302u);
  H.u[2] = __builtin_amdgcn_perm(b[1], b[0], 0x07060302u);
  H.u[3] = __builtin_amdgcn_perm(b[3], b[2], 0x07060302u);
  L.u[0] = __builtin_amdgcn_perm(a[1], a[0], 0x05040100u);
  L.u[1] = __builtin_amdgcn_perm(a[3], a[2], 0x05040100u);
  L.u[2] = __builtin_amdgcn_perm(b[1], b[0], 0x05040100u);
  L.u[3] = __builtin_amdgcn_perm(b[3], b[2], 0x05040100u);
  frag2 f; f.hi = H.s; f.lo = L.s; return f;
}

__device__ __forceinline__ f32x4 mfma16(short8 a, short8 b, f32x4 c) {
  return __builtin_amdgcn_mfma_f32_16x16x32_bf16(a, b, c, 0, 0, 0);
}

// ---------------- pack kernels ----------------

__global__ __launch_bounds__(256) void pack4_kernel(const float4* __restrict__ in,
                                                    u32x4* __restrict__ out, int n4) {
  int i = blockIdx.x * 256 + threadIdx.x;
  if (i < n4) {
    float4 v = in[i];
    u32x4 p;
    p[0] = packsplit(v.x); p[1] = packsplit(v.y);
    p[2] = packsplit(v.z); p[3] = packsplit(v.w);
    out[i] = p;
  }
}

// in: fp32 [R][C] -> out: packed u32 [C][R]
__global__ __launch_bounds__(1024) void pack_t_kernel(const float* __restrict__ in,
                                                      uint32_t* __restrict__ out, int R, int C) {
  __shared__ float tile[64][65];
  int c0 = blockIdx.x * 64, r0 = blockIdx.y * 64;
  int tx = threadIdx.x, ty = threadIdx.y;
  #pragma unroll
  for (int i = 0; i < 4; ++i)
    tile[ty + 16*i][tx] = in[(size_t)(r0 + ty + 16*i)*C + c0 + tx];
  __syncthreads();
  #pragma unroll
  for (int i = 0; i < 4; ++i)
    out[(size_t)(c0 + ty + 16*i)*R + r0 + tx] = packsplit(tile[tx][ty + 16*i]);
}

// ---------------- GEMM (128x128 tile, BK=32, 4 waves, bf16x3 split) ----------------
// A packed [M][K], Bt packed [N][K]. MODE 0: qkv epilogue (scatter packed Q/K/Vt + bias)
// MODE 1: fp32 out + bias.

template<int MODE>
__global__ __launch_bounds__(256) void gemm_split(const uint32_t* __restrict__ A,
                                                  const uint32_t* __restrict__ Bt,
                                                  const float* __restrict__ bias,
                                                  uint32_t* __restrict__ qp,
                                                  uint32_t* __restrict__ kp,
                                                  uint32_t* __restrict__ vtp,
                                                  float* __restrict__ fout,
                                                  int M, int N, int K) {
  __shared__ uint32_t As[128*8*4];   // 128 rows x 8 slots(16B) swizzled
  __shared__ uint32_t Bs[128*8*4];
  int tid = threadIdx.x;
  int w = tid >> 6, l = tid & 63, lg = l >> 4, lr = l & 15;
  int bm = blockIdx.y * 128, bn = blockIdx.x * 128;
  int wm = (w >> 1) * 64, wn = (w & 1) * 64;
  f32x4 zero = {0.f, 0.f, 0.f, 0.f};
  f32x4 acc[4][4];
  #pragma unroll
  for (int i = 0; i < 4; ++i)
    #pragma unroll
    for (int j = 0; j < 4; ++j) acc[i][j] = zero;

  for (int k0 = 0; k0 < K; k0 += 32) {
    #pragma unroll
    for (int i = 0; i < 4; ++i) {
      int s = tid + 256*i;            // 0..1023 slots
      int row = s >> 3, k4 = s & 7;
      int g4 = k4 ^ (row & 7);        // pre-swizzle source granule
      gload_lds16(A  + (size_t)(bm + row)*K + k0 + g4*4, &As[s*4]);
      gload_lds16(Bt + (size_t)(bn + row)*K + k0 + g4*4, &Bs[s*4]);
    }
    __syncthreads();
    frag2 af[4];
    #pragma unroll
    for (int mf = 0; mf < 4; ++mf) {
      int row = wm + mf*16 + lr;
      int sb = row*8;
      int s0 = sb + ((2*lg)   ^ (row & 7));
      int s1 = sb + ((2*lg+1) ^ (row & 7));
      af[mf] = extract2(*(const u32x4*)&As[s0*4], *(const u32x4*)&As[s1*4]);
    }
    #pragma unroll
    for (int nf = 0; nf < 4; ++nf) {
      int row = wn + nf*16 + lr;
      int sb = row*8;
      int s0 = sb + ((2*lg)   ^ (row & 7));
      int s1 = sb + ((2*lg+1) ^ (row & 7));
      frag2 bfr = extract2(*(const u32x4*)&Bs[s0*4], *(const u32x4*)&Bs[s1*4]);
      #pragma unroll
      for (int mf = 0; mf < 4; ++mf) {
        acc[mf][nf] = mfma16(af[mf].hi, bfr.hi, acc[mf][nf]);
        acc[mf][nf] = mfma16(af[mf].hi, bfr.lo, acc[mf][nf]);
        acc[mf][nf] = mfma16(af[mf].lo, bfr.hi, acc[mf][nf]);
      }
    }
    __syncthreads();
  }
  // epilogue: C row = (lg*4+r) group, col = lane&15 (m89-verified layout)
  #pragma unroll
  for (int nf = 0; nf < 4; ++nf) {
    int col = bn + wn + nf*16 + lr;
    float bv = bias[col];
    #pragma unroll
    for (int mf = 0; mf < 4; ++mf) {
      #pragma unroll
      for (int r = 0; r < 4; ++r) {
        int rowm = bm + wm + mf*16 + lg*4 + r;
        float v = acc[mf][nf][r] + bv;
        if (MODE == 1) {
          fout[(size_t)rowm*N + col] = v;
        } else {
          int sec = col >> 10;          // 0=q 1=k 2=v
          int hh  = (col >> 6) & 15;
          int d   = col & 63;
          int b   = rowm >> 11, t = rowm & 2047;
          uint32_t pkv = packsplit(v);
          size_t bhh = (size_t)b*NH + hh;
          if (sec == 0)      qp[(bhh*T_ + t)*HD + d]  = pkv;
          else if (sec == 1) kp[(bhh*T_ + t)*HD + d]  = pkv;
          else               vtp[(bhh*HD + d)*T_ + t] = pkv;  // V stored transposed
        }
      }
    }
  }
}

// ---------------- flash attention (causal) ----------------
// grid (T/64, B*H). 4 waves x 16 q-rows. KV tiles of 64. Online softmax in regs.

__global__ __launch_bounds__(256) void attn_kernel(const uint32_t* __restrict__ qp,
                                                   const uint32_t* __restrict__ kp,
                                                   const uint32_t* __restrict__ vtp,
                                                   uint32_t* __restrict__ ctx) {
  __shared__ uint32_t Kt[64*16*4];    // [kv][d] packed, swizzled slots
  __shared__ uint32_t Vt[64*16*4];    // [d][kv] packed, swizzled slots
  __shared__ uint32_t Pl[4][16*68];   // per-wave P, padded stride 68
  int qt = blockIdx.x, bh = blockIdx.y;
  int tid = threadIdx.x;
  int w = tid >> 6, l = tid & 63, lg = l >> 4, lr = l & 15;
  int q0 = qt * 64;
  // Q frags (A operand: row = lane&15, k = (lane>>4)*8+j + 32*ks)
  const uint32_t* qb = qp + ((size_t)bh*T_ + q0 + w*16 + lr)*HD;
  frag2 qf[2];
  #pragma unroll
  for (int ks = 0; ks < 2; ++ks) {
    u32x4 a = *(const u32x4*)(qb + ks*32 + lg*8);
    u32x4 b = *(const u32x4*)(qb + ks*32 + lg*8 + 4);
    qf[ks] = extract2(a, b);
  }
  f32x4 zero = {0.f, 0.f, 0.f, 0.f};
  f32x4 o[4] = {zero, zero, zero, zero};
  float m_r[4] = {-1e30f, -1e30f, -1e30f, -1e30f};
  float l_r[4] = {0.f, 0.f, 0.f, 0.f};
  uint32_t* pw = &Pl[w][0];

  for (int kt = 0; kt <= qt; ++kt) {
    int kv0 = kt * 64;
    #pragma unroll
    for (int i = 0; i < 4; ++i) {
      int s = tid + 256*i;            // 1024 slots per tile
      int row = s >> 4, k4 = s & 15;
      int g4 = k4 ^ (row & 7);        // swizzle within 128B half
      gload_lds16(kp  + ((size_t)bh*T_ + kv0 + row)*HD + g4*4, &Kt[s*4]);
      gload_lds16(vtp + ((size_t)bh*HD + row)*T_ + kv0 + g4*4, &Vt[s*4]);
    }
    __syncthreads();
    // S = Q K^T / 8
    f32x4 s4[4];
    #pragma unroll
    for (int fc = 0; fc < 4; ++fc) {
      f32x4 acc = zero;
      #pragma unroll
      for (int ks = 0; ks < 2; ++ks) {
        int row = fc*16 + lr;         // kv row in tile (B operand n-index)
        int sb = row*16 + ks*8;
        int s0 = sb + ((2*lg)   ^ (row & 7));
        int s1 = sb + ((2*lg+1) ^ (row & 7));
        frag2 kf = extract2(*(const u32x4*)&Kt[s0*4], *(const u32x4*)&Kt[s1*4]);
        acc = mfma16(qf[ks].hi, kf.hi, acc);
        acc = mfma16(qf[ks].hi, kf.lo, acc);
        acc = mfma16(qf[ks].lo, kf.hi, acc);
      }
      s4[fc] = acc * 0.125f;
    }
    if (kt == qt) {                   // diagonal tile: elementwise causal mask
      #pragma unroll
      for (int fc = 0; fc < 4; ++fc)
        #pragma unroll
        for (int r = 0; r < 4; ++r) {
          int col = kv0 + fc*16 + lr;
          int rw  = q0 + w*16 + lg*4 + r;
          if (col > rw) s4[fc][r] = -1e30f;
        }
    }
    // online softmax (rows live in 16-lane groups; reg r = row lg*4+r)
    float sc[4];
    #pragma unroll
    for (int r = 0; r < 4; ++r) {
      float v = fmaxf(fmaxf(s4[0][r], s4[1][r]), fmaxf(s4[2][r], s4[3][r]));
      v = fmaxf(v, __shfl_xor(v, 1));
      v = fmaxf(v, __shfl_xor(v, 2));
      v = fmaxf(v, __shfl_xor(v, 4));
      v = fmaxf(v, __shfl_xor(v, 8));
      float mn = fmaxf(m_r[r], v);
      sc[r] = __expf(m_r[r] - mn);
      m_r[r] = mn;
    }
    float sum[4] = {0.f, 0.f, 0.f, 0.f};
    #pragma unroll
    for (int fc = 0; fc < 4; ++fc)
      #pragma unroll
      for (int r = 0; r < 4; ++r) {
        float p = __expf(s4[fc][r] - m_r[r]);
        s4[fc][r] = p;
        sum[r] += p;
      }
    #pragma unroll
    for (int r = 0; r < 4; ++r) {
      float v = sum[r];
      v += __shfl_xor(v, 1); v += __shfl_xor(v, 2);
      v += __shfl_xor(v, 4); v += __shfl_xor(v, 8);
      l_r[r] = l_r[r]*sc[r] + v;
    }
    #pragma unroll
    for (int df = 0; df < 4; ++df)
      #pragma unroll
      for (int r = 0; r < 4; ++r) o[df][r] *= sc[r];
    // pack P to per-wave LDS (D-layout write, A-layout read)
    #pragma unroll
    for (int fc = 0; fc < 4; ++fc)
      #pragma unroll
      for (int r = 0; r < 4; ++r)
        pw[(lg*4 + r)*68 + fc*16 + lr] = packsplit(s4[fc][r]);
    __builtin_amdgcn_sched_barrier(0);   // keep ds_reads after ds_writes (wave-local)
    frag2 pf[2];
    #pragma unroll
    for (int ks = 0; ks < 2; ++ks) {
      const uint32_t* pr = pw + lr*68 + ks*32 + lg*8;
      pf[ks] = extract2(*(const u32x4*)pr, *(const u32x4*)(pr + 4));
    }
    // O += P V
    #pragma unroll
    for (int df = 0; df < 4; ++df) {
      #pragma unroll
      for (int ks = 0; ks < 2; ++ks) {
        int row = df*16 + lr;         // d row in Vt tile (B operand n-index)
        int sb = row*16 + ks*8;
        int s0 = sb + ((2*lg)   ^ (row & 7));
        int s1 = sb + ((2*lg+1) ^ (row & 7));
        frag2 vf = extract2(*(const u32x4*)&Vt[s0*4], *(const u32x4*)&Vt[s1*4]);
        o[df] = mfma16(pf[ks].hi, vf.hi, o[df]);
        o[df] = mfma16(pf[ks].hi, vf.lo, o[df]);
        o[df] = mfma16(pf[ks].lo, vf.hi, o[df]);
      }
    }
    __syncthreads();                  // all waves done with K/V before restage
  }
  // epilogue: ctx[b][t][h*64+d] packed
  int b = bh >> 4, h = bh & 15;
  float inv[4];
  #pragma unroll
  for (int r = 0; r < 4; ++r) inv[r] = 1.0f / l_r[r];
  #pragma unroll
  for (int df = 0; df < 4; ++df)
    #pragma unroll
    for (int r = 0; r < 4; ++r) {
      int q = q0 + w*16 + lg*4 + r;
      ctx[((size_t)b*T_ + q)*C_ + h*HD + df*16 + lr] = packsplit(o[df][r] * inv[r]);
    }
}

// ---------------- launch ----------------

extern "C" void kernel_launch(void* const* d_in, const int* in_sizes, int n_in,
                              void* d_out, int out_size, void* d_ws, size_t ws_size,
                              hipStream_t stream) {
  (void)in_sizes; (void)n_in; (void)out_size; (void)ws_size;
  const float* x      = (const float*)d_in[0];
  const float* w_qkv  = (const float*)d_in[1];
  const float* b_qkv  = (const float*)d_in[2];
  const float* w_proj = (const float*)d_in[3];
  const float* b_proj = (const float*)d_in[4];
  float* out = (float*)d_out;

  uint8_t* ws = (uint8_t*)d_ws;
  const size_t MB = (size_t)1 << 20;
  uint32_t* xp  = (uint32_t*)(ws + 0);       // 16MB packed x [M][C]
  uint32_t* ctx = xp;                        // aliased: attn output (x dead by then)
  uint32_t* wqt = (uint32_t*)(ws + 16*MB);   // 12MB packed w_qkv^T [3C][C]
  uint32_t* wpt = (uint32_t*)(ws + 28*MB);   //  4MB packed w_proj^T [C][C]
  uint32_t* qp  = (uint32_t*)(ws + 32*MB);   // 16MB Q packed [BH][T][HD]
  uint32_t* kp  = (uint32_t*)(ws + 48*MB);   // 16MB K packed
  uint32_t* vtp = (uint32_t*)(ws + 64*MB);   // 16MB V packed transposed [BH][HD][T]
  // total 80MB workspace

  pack4_kernel<<<(M_*C_/4 + 255)/256, 256, 0, stream>>>((const float4*)x, (u32x4*)xp, M_*C_/4);
  pack_t_kernel<<<dim3(3*C_/64, C_/64), dim3(64, 16), 0, stream>>>(w_qkv, wqt, C_, 3*C_);
  pack_t_kernel<<<dim3(C_/64, C_/64), dim3(64, 16), 0, stream>>>(w_proj, wpt, C_, C_);
  gemm_split<0><<<dim3(3*C_/128, M_/128), 256, 0, stream>>>(
      xp, wqt, b_qkv, qp, kp, vtp, nullptr, M_, 3*C_, C_);
  attn_kernel<<<dim3(T_/64, BH_), 256, 0, stream>>>(qp, kp, vtp, ctx);
  gemm_split<1><<<dim3(C_/128, M_/128), 256, 0, stream>>>(
      ctx, wpt, b_proj, nullptr, nullptr, nullptr, out, M_, C_, C_);
}

// Round 3
// 384.091 us; speedup vs baseline: 1.0750x; 1.0750x over previous
//
#include <hip/hip_runtime.h>
#include <stdint.h>

// MultiHeadSelfAttention: B=2 T=2048 C=1024 H=16 D=64, fp32 in/out.
// Split-precision bf16x3 MFMA (x = hi+lo bf16; a*b ~= ah*bh + ah*bl + al*bh).
// R2: all operands stored as SEPARATE bf16 hi/lo planes (no v_perm extraction),
// XOR-swizzled LDS everywhere, attention double-buffers K/V with prefetch and
// one barrier per tile, P kept f32 in LDS and split on read via v_cvt_pk_bf16_f32,
// XCD-grouped longest-first block mapping for the causal imbalance.
// (R3 = R2 resubmitted verbatim: R2 bench was an infra GPU-acquisition timeout.)

#define B_  2
#define T_  2048
#define C_  1024
#define NH  16
#define HD  64
#define BH_ (B_*NH)   // 32
#define M_  (B_*T_)   // 4096

typedef __attribute__((ext_vector_type(8))) short short8;
typedef __attribute__((ext_vector_type(4))) float f32x4;
typedef __attribute__((ext_vector_type(4))) uint32_t u32x4;

typedef const __attribute__((address_space(1))) void* gas_ptr;
typedef __attribute__((address_space(3))) void* las_ptr;

__device__ __forceinline__ void gload_lds16(const void* g, void* l) {
  __builtin_amdgcn_global_load_lds((gas_ptr)g, (las_ptr)l, 16, 0, 0);
}

__device__ __forceinline__ unsigned short rne16(float x){
  uint32_t v = __float_as_uint(x);
  return (unsigned short)((v + 0x7fffu + ((v >> 16) & 1u)) >> 16);
}

__device__ __forceinline__ uint32_t cvtpk_bf16(float a, float b){
  uint32_t r;
  asm("v_cvt_pk_bf16_f32 %0, %1, %2" : "=v"(r) : "v"(a), "v"(b));
  return r;   // low16 = bf16(a), high16 = bf16(b)
}

// 8 f32 (two granules) -> bf16 hi-frag (truncation)
__device__ __forceinline__ short8 hi8(u32x4 a, u32x4 b){
  union { u32x4 u; short8 s; } H;
  H.u[0] = __builtin_amdgcn_perm(a[1], a[0], 0x07060302u);
  H.u[1] = __builtin_amdgcn_perm(a[3], a[2], 0x07060302u);
  H.u[2] = __builtin_amdgcn_perm(b[1], b[0], 0x07060302u);
  H.u[3] = __builtin_amdgcn_perm(b[3], b[2], 0x07060302u);
  return H.s;
}
// 8 f32 -> bf16 lo-frag (residual, RNE)
__device__ __forceinline__ short8 lo8(u32x4 a, u32x4 b){
  float l0 = __uint_as_float(a[0]) - __uint_as_float(a[0] & 0xffff0000u);
  float l1 = __uint_as_float(a[1]) - __uint_as_float(a[1] & 0xffff0000u);
  float l2 = __uint_as_float(a[2]) - __uint_as_float(a[2] & 0xffff0000u);
  float l3 = __uint_as_float(a[3]) - __uint_as_float(a[3] & 0xffff0000u);
  float l4 = __uint_as_float(b[0]) - __uint_as_float(b[0] & 0xffff0000u);
  float l5 = __uint_as_float(b[1]) - __uint_as_float(b[1] & 0xffff0000u);
  float l6 = __uint_as_float(b[2]) - __uint_as_float(b[2] & 0xffff0000u);
  float l7 = __uint_as_float(b[3]) - __uint_as_float(b[3] & 0xffff0000u);
  union { u32x4 u; short8 s; } L;
  L.u[0] = cvtpk_bf16(l0, l1);
  L.u[1] = cvtpk_bf16(l2, l3);
  L.u[2] = cvtpk_bf16(l4, l5);
  L.u[3] = cvtpk_bf16(l6, l7);
  return L.s;
}

__device__ __forceinline__ f32x4 mfma16(short8 a, short8 b, f32x4 c) {
  return __builtin_amdgcn_mfma_f32_16x16x32_bf16(a, b, c, 0, 0, 0);
}

// ---------------- pack kernels ----------------

__global__ __launch_bounds__(256) void pack4_kernel(const float4* __restrict__ in,
                                                    unsigned short* __restrict__ oh,
                                                    unsigned short* __restrict__ ol, int n4) {
  int i = blockIdx.x * 256 + threadIdx.x;
  if (i < n4) {
    float4 v = in[i];
    float f[4] = {v.x, v.y, v.z, v.w};
    ushort4 h, lo;
    unsigned short hh[4], ll[4];
    #pragma unroll
    for (int j=0;j<4;++j){
      uint32_t bt = __float_as_uint(f[j]);
      hh[j] = (unsigned short)(bt >> 16);
      ll[j] = rne16(f[j] - __uint_as_float(bt & 0xffff0000u));
    }
    h.x=hh[0]; h.y=hh[1]; h.z=hh[2]; h.w=hh[3];
    lo.x=ll[0]; lo.y=ll[1]; lo.z=ll[2]; lo.w=ll[3];
    *(ushort4*)(oh + (size_t)i*4) = h;
    *(ushort4*)(ol + (size_t)i*4) = lo;
  }
}

// in: fp32 [R][C] -> out planes: [C][R] (transposed), bf16 hi/lo
__global__ __launch_bounds__(1024) void pack_t_kernel(const float* __restrict__ in,
                                                      unsigned short* __restrict__ oh,
                                                      unsigned short* __restrict__ ol,
                                                      int R, int C) {
  __shared__ float tile[64][65];
  int c0 = blockIdx.x * 64, r0 = blockIdx.y * 64;
  int tx = threadIdx.x, ty = threadIdx.y;
  #pragma unroll
  for (int i = 0; i < 4; ++i)
    tile[ty + 16*i][tx] = in[(size_t)(r0 + ty + 16*i)*C + c0 + tx];
  __syncthreads();
  #pragma unroll
  for (int i = 0; i < 4; ++i) {
    float v = tile[tx][ty + 16*i];
    uint32_t bt = __float_as_uint(v);
    size_t o = (size_t)(c0 + ty + 16*i)*R + r0 + tx;
    oh[o] = (unsigned short)(bt >> 16);
    ol[o] = rne16(v - __uint_as_float(bt & 0xffff0000u));
  }
}

// ---------------- GEMM (128x128 tile, BK=32, 4 waves, hi/lo planes) ----------------
// A planes [M][K], Bt planes [N][K].
// LDS row r = [hi 64B | lo 64B] = 8 granules of 16B, granule position = u ^ (r&7).
// MODE 0: qkv epilogue (scatter Q(scaled)/K/Vt hi-lo planes + bias); MODE 1: fp32 out.

template<int MODE>
__global__ __launch_bounds__(256) void gemm_planes(
    const unsigned short* __restrict__ Ah, const unsigned short* __restrict__ Al,
    const unsigned short* __restrict__ Bh, const unsigned short* __restrict__ Bl,
    const float* __restrict__ bias,
    unsigned short* __restrict__ qh, unsigned short* __restrict__ ql,
    unsigned short* __restrict__ kh, unsigned short* __restrict__ kl,
    unsigned short* __restrict__ vth, unsigned short* __restrict__ vtl,
    float* __restrict__ fout, int M, int N, int K) {
  __shared__ unsigned short As[128*64];   // 128 rows x 128B
  __shared__ unsigned short Bs[128*64];
  int tid = threadIdx.x;
  int w = tid >> 6, l = tid & 63, lg = l >> 4, lr = l & 15, lr7 = lr & 7;
  int bm = blockIdx.y * 128, bn = blockIdx.x * 128;
  int wm = (w >> 1) * 64, wn = (w & 1) * 64;

  // staging sources (pre-swizzled: LDS slot s -> plane granule u = (s&7)^(row&7))
  const unsigned short* asrc[4]; const unsigned short* bsrc[4];
  #pragma unroll
  for (int i = 0; i < 4; ++i) {
    int s = tid + 256*i; int r = s >> 3, p = s & 7, u = p ^ (r & 7);
    asrc[i] = ((u < 4) ? Ah : Al) + (size_t)(bm + r)*K + (u & 3)*8;
    bsrc[i] = ((u < 4) ? Bh : Bl) + (size_t)(bn + r)*K + (u & 3)*8;
  }
  // fragment read byte-offsets (hi; lo = ^64)
  int aoh[4], boh[4];
  #pragma unroll
  for (int f = 0; f < 4; ++f) {
    aoh[f] = (wm + f*16 + lr)*128 + ((lg ^ lr7)*16);
    boh[f] = (wn + f*16 + lr)*128 + ((lg ^ lr7)*16);
  }

  f32x4 zero = {0.f, 0.f, 0.f, 0.f};
  f32x4 acc[4][4];
  #pragma unroll
  for (int i = 0; i < 4; ++i)
    #pragma unroll
    for (int j = 0; j < 4; ++j) acc[i][j] = zero;

  for (int k0 = 0; k0 < K; k0 += 32) {
    #pragma unroll
    for (int i = 0; i < 4; ++i) {
      int s = tid + 256*i;
      gload_lds16(asrc[i], (char*)As + (size_t)s*16);
      gload_lds16(bsrc[i], (char*)Bs + (size_t)s*16);
      asrc[i] += 32; bsrc[i] += 32;
    }
    __syncthreads();
    short8 ahf[4], alf[4];
    #pragma unroll
    for (int mf = 0; mf < 4; ++mf) {
      ahf[mf] = *(const short8*)((const char*)As + aoh[mf]);
      alf[mf] = *(const short8*)((const char*)As + (aoh[mf] ^ 64));
    }
    #pragma unroll
    for (int nf = 0; nf < 4; ++nf) {
      short8 bhf = *(const short8*)((const char*)Bs + boh[nf]);
      short8 blf = *(const short8*)((const char*)Bs + (boh[nf] ^ 64));
      #pragma unroll
      for (int mf = 0; mf < 4; ++mf) {
        acc[mf][nf] = mfma16(ahf[mf], bhf, acc[mf][nf]);
        acc[mf][nf] = mfma16(ahf[mf], blf, acc[mf][nf]);
        acc[mf][nf] = mfma16(alf[mf], bhf, acc[mf][nf]);
      }
    }
    __syncthreads();
  }
  // epilogue: D row = lg*4+r, col = lr (m89 layout)
  #pragma unroll
  for (int nf = 0; nf < 4; ++nf) {
    int col = bn + wn + nf*16 + lr;
    float bv = bias[col];
    #pragma unroll
    for (int mf = 0; mf < 4; ++mf) {
      #pragma unroll
      for (int r = 0; r < 4; ++r) {
        int rowm = bm + wm + mf*16 + lg*4 + r;
        float v = acc[mf][nf][r] + bv;
        if (MODE == 1) {
          fout[(size_t)rowm*N + col] = v;
        } else {
          int sec = col >> 10;          // 0=q 1=k 2=v
          int hh  = (col >> 6) & 15;
          int d   = col & 63;
          int b   = rowm >> 11, t = rowm & 2047;
          size_t bhh = (size_t)b*NH + hh;
          if (sec == 0) v *= 0.125f;    // fold 1/sqrt(HD) into Q
          uint32_t bt = __float_as_uint(v);
          unsigned short h16 = (unsigned short)(bt >> 16);
          unsigned short l16 = rne16(v - __uint_as_float(bt & 0xffff0000u));
          if (sec == 0)      { size_t o = (bhh*T_ + t)*HD + d;  qh[o] = h16;  ql[o] = l16; }
          else if (sec == 1) { size_t o = (bhh*T_ + t)*HD + d;  kh[o] = h16;  kl[o] = l16; }
          else               { size_t o = (bhh*HD + d)*T_ + t;  vth[o] = h16; vtl[o] = l16; }
        }
      }
    }
  }
}

// ---------------- flash attention (causal) ----------------
// 1024 blocks; bx -> (xcd-grouped bh, longest-first qt). 4 waves x 16 q-rows,
// KV tiles 64, K/V double-buffered + prefetch, one barrier per tile.
// LDS K/V row = [hi 128B | lo 128B] = 16 granules; pos = (u&8)|((u&7)^(r&7)).
// P: per-wave f32 [16][64], granule pos = u ^ q; split to bf16 on read.

__global__ __launch_bounds__(256) void attn_kernel(
    const unsigned short* __restrict__ qh, const unsigned short* __restrict__ ql,
    const unsigned short* __restrict__ kh, const unsigned short* __restrict__ kl,
    const unsigned short* __restrict__ vth, const unsigned short* __restrict__ vtl,
    unsigned short* __restrict__ ctxh, unsigned short* __restrict__ ctxl) {
  __shared__ unsigned short Kt[2][64*128];  // 2 x 16KB
  __shared__ unsigned short Vt[2][64*128];  // 2 x 16KB
  __shared__ float Pf[4][1024];             // per-wave 4KB
  int bx = blockIdx.x;
  int xcd = bx & 7, jj = bx >> 3;
  int bh = xcd*4 + (jj >> 5);               // 4 heads per XCD (K/V set = 4MB = L2)
  int qt = 31 - (jj & 31);                  // longest-first
  int tid = threadIdx.x;
  int w = tid >> 6, l = tid & 63, lg = l >> 4, lr = l & 15, lr7 = lr & 7;
  int q0 = qt * 64;

  // Q frags: direct plane loads (Q pre-scaled by 0.125)
  const unsigned short* qbh = qh + ((size_t)bh*T_ + q0 + w*16 + lr)*HD;
  const unsigned short* qbl = ql + ((size_t)bh*T_ + q0 + w*16 + lr)*HD;
  short8 qfh[2], qfl[2];
  #pragma unroll
  for (int ks = 0; ks < 2; ++ks) {
    qfh[ks] = *(const short8*)(qbh + ks*32 + lg*8);
    qfl[ks] = *(const short8*)(qbl + ks*32 + lg*8);
  }

  // staging sources
  const unsigned short* ksrc[4]; const unsigned short* vsrc[4];
  #pragma unroll
  for (int i = 0; i < 4; ++i) {
    int s = tid + 256*i; int r = s >> 4, p = s & 15;
    int u = (p & 8) | ((p & 7) ^ (r & 7));
    ksrc[i] = ((u < 8) ? kh : kl) + ((size_t)bh*T_ + r)*HD + (u & 7)*8;
    vsrc[i] = ((u < 8) ? vth : vtl) + ((size_t)bh*HD + r)*T_ + (u & 7)*8;
  }
  auto stage = [&](int buf) {
    #pragma unroll
    for (int i = 0; i < 4; ++i) {
      int s = tid + 256*i;
      gload_lds16(ksrc[i], (char*)&Kt[buf][0] + (size_t)s*16);
      gload_lds16(vsrc[i], (char*)&Vt[buf][0] + (size_t)s*16);
    }
    #pragma unroll
    for (int i = 0; i < 4; ++i) { ksrc[i] += 64*HD; vsrc[i] += 64; }
  };

  // K/V fragment read offsets (same formula for K rows=kv and V rows=d); lo = +128
  int koff[4][2];
  #pragma unroll
  for (int fc = 0; fc < 4; ++fc)
    #pragma unroll
    for (int ks = 0; ks < 2; ++ks)
      koff[fc][ks] = (fc*16 + lr)*256 + (((ks*4 + lg) ^ lr7)*16);
  // P write offsets (16) and read offsets (4)
  int pwoff[16];
  #pragma unroll
  for (int fc = 0; fc < 4; ++fc)
    #pragma unroll
    for (int r = 0; r < 4; ++r) {
      int q = lg*4 + r;
      int u = fc*4 + (lr >> 2);
      pwoff[fc*4 + r] = q*256 + ((u ^ q)*16) + (lr & 3)*4;
    }
  int proff[2][2];
  #pragma unroll
  for (int ks = 0; ks < 2; ++ks)
    #pragma unroll
    for (int g = 0; g < 2; ++g)
      proff[ks][g] = lr*256 + (((ks*8 + lg*2 + g) ^ lr)*16);

  f32x4 zero = {0.f, 0.f, 0.f, 0.f};
  f32x4 o[4] = {zero, zero, zero, zero};
  float m_r[4] = {-1e30f, -1e30f, -1e30f, -1e30f};
  float l_r[4] = {0.f, 0.f, 0.f, 0.f};
  char* PW = (char*)&Pf[w][0];

  stage(0);
  __syncthreads();
  int cur = 0;

  for (int kt = 0; kt <= qt; ++kt) {
    if (kt < qt) stage(cur ^ 1);            // prefetch next tile
    const char* KB = (const char*)&Kt[cur][0];
    const char* VB = (const char*)&Vt[cur][0];
    // S = Q K^T (scale folded into Q)
    f32x4 s4[4];
    #pragma unroll
    for (int fc = 0; fc < 4; ++fc) {
      f32x4 acc = zero;
      #pragma unroll
      for (int ks = 0; ks < 2; ++ks) {
        short8 khf = *(const short8*)(KB + koff[fc][ks]);
        short8 klf = *(const short8*)(KB + koff[fc][ks] + 128);
        acc = mfma16(qfh[ks], khf, acc);
        acc = mfma16(qfh[ks], klf, acc);
        acc = mfma16(qfl[ks], khf, acc);
      }
      s4[fc] = acc;
    }
    if (kt == qt) {                         // diagonal: elementwise causal mask
      #pragma unroll
      for (int fc = 0; fc < 4; ++fc)
        #pragma unroll
        for (int r = 0; r < 4; ++r) {
          int col = q0 + fc*16 + lr;        // kv0 == q0 on the diagonal
          int rw  = q0 + w*16 + lg*4 + r;
          if (col > rw) s4[fc][r] = -1e30f;
        }
    }
    // online softmax (row q = lg*4+r; kv across {fc} x 16 lanes)
    float sc[4];
    #pragma unroll
    for (int r = 0; r < 4; ++r) {
      float v = fmaxf(fmaxf(s4[0][r], s4[1][r]), fmaxf(s4[2][r], s4[3][r]));
      v = fmaxf(v, __shfl_xor(v, 1));
      v = fmaxf(v, __shfl_xor(v, 2));
      v = fmaxf(v, __shfl_xor(v, 4));
      v = fmaxf(v, __shfl_xor(v, 8));
      float mn = fmaxf(m_r[r], v);
      sc[r] = __expf(m_r[r] - mn);
      m_r[r] = mn;
    }
    float sum[4] = {0.f, 0.f, 0.f, 0.f};
    #pragma unroll
    for (int fc = 0; fc < 4; ++fc)
      #pragma unroll
      for (int r = 0; r < 4; ++r) {
        float p = __expf(s4[fc][r] - m_r[r]);
        s4[fc][r] = p;
        sum[r] += p;
      }
    #pragma unroll
    for (int r = 0; r < 4; ++r) {
      float v = sum[r];
      v += __shfl_xor(v, 1); v += __shfl_xor(v, 2);
      v += __shfl_xor(v, 4); v += __shfl_xor(v, 8);
      l_r[r] = l_r[r]*sc[r] + v;
    }
    #pragma unroll
    for (int df = 0; df < 4; ++df)
      #pragma unroll
      for (int r = 0; r < 4; ++r) o[df][r] *= sc[r];
    // P -> per-wave LDS (f32, swizzled, conflict-free)
    #pragma unroll
    for (int fc = 0; fc < 4; ++fc)
      #pragma unroll
      for (int r = 0; r < 4; ++r)
        *(float*)(PW + pwoff[fc*4 + r]) = s4[fc][r];
    __builtin_amdgcn_sched_barrier(0);      // wave-local write->read ordering
    short8 pah[2], pal[2];
    #pragma unroll
    for (int ks = 0; ks < 2; ++ks) {
      u32x4 a = *(const u32x4*)(PW + proff[ks][0]);
      u32x4 b = *(const u32x4*)(PW + proff[ks][1]);
      pah[ks] = hi8(a, b);
      pal[ks] = lo8(a, b);
    }
    // O += P V
    #pragma unroll
    for (int df = 0; df < 4; ++df) {
      #pragma unroll
      for (int ks = 0; ks < 2; ++ks) {
        short8 vhf = *(const short8*)(VB + koff[df][ks]);
        short8 vlf = *(const short8*)(VB + koff[df][ks] + 128);
        o[df] = mfma16(pah[ks], vhf, o[df]);
        o[df] = mfma16(pah[ks], vlf, o[df]);
        o[df] = mfma16(pal[ks], vhf, o[df]);
      }
    }
    __syncthreads();                        // staged next buf ready; cur free
    cur ^= 1;
  }
  // epilogue: ctx planes [b][t][h*64+d]
  int b = bh >> 4, h = bh & 15;
  float inv[4];
  #pragma unroll
  for (int r = 0; r < 4; ++r) inv[r] = 1.0f / l_r[r];
  #pragma unroll
  for (int df = 0; df < 4; ++df)
    #pragma unroll
    for (int r = 0; r < 4; ++r) {
      int q = q0 + w*16 + lg*4 + r;
      float v = o[df][r] * inv[r];
      uint32_t bt = __float_as_uint(v);
      size_t oo = ((size_t)b*T_ + q)*C_ + h*HD + df*16 + lr;
      ctxh[oo] = (unsigned short)(bt >> 16);
      ctxl[oo] = rne16(v - __uint_as_float(bt & 0xffff0000u));
    }
}

// ---------------- launch ----------------

extern "C" void kernel_launch(void* const* d_in, const int* in_sizes, int n_in,
                              void* d_out, int out_size, void* d_ws, size_t ws_size,
                              hipStream_t stream) {
  (void)in_sizes; (void)n_in; (void)out_size; (void)ws_size;
  const float* x      = (const float*)d_in[0];
  const float* w_qkv  = (const float*)d_in[1];
  const float* b_qkv  = (const float*)d_in[2];
  const float* w_proj = (const float*)d_in[3];
  const float* b_proj = (const float*)d_in[4];
  float* out = (float*)d_out;

  uint8_t* ws = (uint8_t*)d_ws;
  const size_t MB = (size_t)1 << 20;
  unsigned short* xh  = (unsigned short*)(ws + 0);      // 8MB  [M][C] hi
  unsigned short* xl  = (unsigned short*)(ws + 8*MB);   // 8MB  lo
  unsigned short* cth = xh;                             // ctx aliases x (dead)
  unsigned short* ctl = xl;
  unsigned short* wqh = (unsigned short*)(ws + 16*MB);  // 6MB  w_qkv^T hi [3C][C]
  unsigned short* wql = (unsigned short*)(ws + 22*MB);  // 6MB
  unsigned short* wph = (unsigned short*)(ws + 28*MB);  // 2MB  w_proj^T hi [C][C]
  unsigned short* wpl = (unsigned short*)(ws + 30*MB);  // 2MB
  unsigned short* qhp = (unsigned short*)(ws + 32*MB);  // 8MB  Q hi [BH][T][HD] (x0.125)
  unsigned short* qlp = (unsigned short*)(ws + 40*MB);  // 8MB
  unsigned short* khp = (unsigned short*)(ws + 48*MB);  // 8MB  K hi
  unsigned short* klp = (unsigned short*)(ws + 56*MB);  // 8MB
  unsigned short* vth = (unsigned short*)(ws + 64*MB);  // 8MB  V^T hi [BH][HD][T]
  unsigned short* vtl = (unsigned short*)(ws + 72*MB);  // 8MB   -> 80MB total

  pack4_kernel<<<(M_*C_/4 + 255)/256, 256, 0, stream>>>((const float4*)x, xh, xl, M_*C_/4);
  pack_t_kernel<<<dim3(3*C_/64, C_/64), dim3(64, 16), 0, stream>>>(w_qkv, wqh, wql, C_, 3*C_);
  pack_t_kernel<<<dim3(C_/64, C_/64), dim3(64, 16), 0, stream>>>(w_proj, wph, wpl, C_, C_);
  gemm_planes<0><<<dim3(3*C_/128, M_/128), 256, 0, stream>>>(
      xh, xl, wqh, wql, b_qkv, qhp, qlp, khp, klp, vth, vtl, nullptr, M_, 3*C_, C_);
  attn_kernel<<<dim3(1024), 256, 0, stream>>>(qhp, qlp, khp, klp, vth, vtl, cth, ctl);
  gemm_planes<1><<<dim3(C_/128, M_/128), 256, 0, stream>>>(
      cth, ctl, wph, wpl, b_proj, nullptr, nullptr, nullptr, nullptr, nullptr, nullptr,
      out, M_, C_, C_);
}

// Round 9
// 355.219 us; speedup vs baseline: 1.1624x; 1.0813x over previous
//
#include <hip/hip_runtime.h>
#include <stdint.h>

// MultiHeadSelfAttention: B=2 T=2048 C=1024 H=16 D=64, fp32 in/out.
// Split-precision bf16x3 MFMA (x = hi+lo bf16; a*b ~= ah*bh + ah*bl + al*bh).
// R4: attention restructured to swapped-operand MFMA (S^T = K*Q^T, O^T = V^T*P^T):
//  - softmax per-lane scalar (q = lane&15), 4 shfls/tile instead of 32
//  - P stays in registers: cvt_pk_bf16 + 8 __shfl redistribution (P-LDS eliminated)
//  - KV tile 32, LDS 32KB -> 4 blocks/CU (16 waves), defer-max rescale (THR=8)
//  - balanced co-resident qt mapping {j,15-j,16+j,31-j}; bh grouped per XCD (L2)
// GEMMs/packs unchanged from R3.
// (R9 = R4 resubmitted verbatim: R4-R8 benches were infra GPU-acquisition
//  timeouts. GEMM left untouched deliberately: per learn_hip m99/m100 the
//  queued dbuf edit is expected-neutral on this structure; the real lever
//  (8-phase, T3+T4) needs real counters first.)

#define B_  2
#define T_  2048
#define C_  1024
#define NH  16
#define HD  64
#define BH_ (B_*NH)   // 32
#define M_  (B_*T_)   // 4096

typedef __attribute__((ext_vector_type(8))) short short8;
typedef __attribute__((ext_vector_type(4))) float f32x4;
typedef __attribute__((ext_vector_type(4))) uint32_t u32x4;

typedef const __attribute__((address_space(1))) void* gas_ptr;
typedef __attribute__((address_space(3))) void* las_ptr;

__device__ __forceinline__ void gload_lds16(const void* g, void* l) {
  __builtin_amdgcn_global_load_lds((gas_ptr)g, (las_ptr)l, 16, 0, 0);
}

__device__ __forceinline__ unsigned short rne16(float x){
  uint32_t v = __float_as_uint(x);
  return (unsigned short)((v + 0x7fffu + ((v >> 16) & 1u)) >> 16);
}

__device__ __forceinline__ uint32_t cvtpk_bf16(float a, float b){
  uint32_t r;
  asm("v_cvt_pk_bf16_f32 %0, %1, %2" : "=v"(r) : "v"(a), "v"(b));
  return r;   // low16 = bf16(a), high16 = bf16(b)
}

__device__ __forceinline__ f32x4 mfma16(short8 a, short8 b, f32x4 c) {
  return __builtin_amdgcn_mfma_f32_16x16x32_bf16(a, b, c, 0, 0, 0);
}

// ---------------- pack kernels (unchanged) ----------------

__global__ __launch_bounds__(256) void pack4_kernel(const float4* __restrict__ in,
                                                    unsigned short* __restrict__ oh,
                                                    unsigned short* __restrict__ ol, int n4) {
  int i = blockIdx.x * 256 + threadIdx.x;
  if (i < n4) {
    float4 v = in[i];
    float f[4] = {v.x, v.y, v.z, v.w};
    ushort4 h, lo;
    unsigned short hh[4], ll[4];
    #pragma unroll
    for (int j=0;j<4;++j){
      uint32_t bt = __float_as_uint(f[j]);
      hh[j] = (unsigned short)(bt >> 16);
      ll[j] = rne16(f[j] - __uint_as_float(bt & 0xffff0000u));
    }
    h.x=hh[0]; h.y=hh[1]; h.z=hh[2]; h.w=hh[3];
    lo.x=ll[0]; lo.y=ll[1]; lo.z=ll[2]; lo.w=ll[3];
    *(ushort4*)(oh + (size_t)i*4) = h;
    *(ushort4*)(ol + (size_t)i*4) = lo;
  }
}

__global__ __launch_bounds__(1024) void pack_t_kernel(const float* __restrict__ in,
                                                      unsigned short* __restrict__ oh,
                                                      unsigned short* __restrict__ ol,
                                                      int R, int C) {
  __shared__ float tile[64][65];
  int c0 = blockIdx.x * 64, r0 = blockIdx.y * 64;
  int tx = threadIdx.x, ty = threadIdx.y;
  #pragma unroll
  for (int i = 0; i < 4; ++i)
    tile[ty + 16*i][tx] = in[(size_t)(r0 + ty + 16*i)*C + c0 + tx];
  __syncthreads();
  #pragma unroll
  for (int i = 0; i < 4; ++i) {
    float v = tile[tx][ty + 16*i];
    uint32_t bt = __float_as_uint(v);
    size_t o = (size_t)(c0 + ty + 16*i)*R + r0 + tx;
    oh[o] = (unsigned short)(bt >> 16);
    ol[o] = rne16(v - __uint_as_float(bt & 0xffff0000u));
  }
}

// ---------------- GEMM (unchanged from R3) ----------------

template<int MODE>
__global__ __launch_bounds__(256) void gemm_planes(
    const unsigned short* __restrict__ Ah, const unsigned short* __restrict__ Al,
    const unsigned short* __restrict__ Bh, const unsigned short* __restrict__ Bl,
    const float* __restrict__ bias,
    unsigned short* __restrict__ qh, unsigned short* __restrict__ ql,
    unsigned short* __restrict__ kh, unsigned short* __restrict__ kl,
    unsigned short* __restrict__ vth, unsigned short* __restrict__ vtl,
    float* __restrict__ fout, int M, int N, int K) {
  __shared__ unsigned short As[128*64];   // 128 rows x 128B
  __shared__ unsigned short Bs[128*64];
  int tid = threadIdx.x;
  int w = tid >> 6, l = tid & 63, lg = l >> 4, lr = l & 15, lr7 = lr & 7;
  int bm = blockIdx.y * 128, bn = blockIdx.x * 128;
  int wm = (w >> 1) * 64, wn = (w & 1) * 64;

  const unsigned short* asrc[4]; const unsigned short* bsrc[4];
  #pragma unroll
  for (int i = 0; i < 4; ++i) {
    int s = tid + 256*i; int r = s >> 3, p = s & 7, u = p ^ (r & 7);
    asrc[i] = ((u < 4) ? Ah : Al) + (size_t)(bm + r)*K + (u & 3)*8;
    bsrc[i] = ((u < 4) ? Bh : Bl) + (size_t)(bn + r)*K + (u & 3)*8;
  }
  int aoh[4], boh[4];
  #pragma unroll
  for (int f = 0; f < 4; ++f) {
    aoh[f] = (wm + f*16 + lr)*128 + ((lg ^ lr7)*16);
    boh[f] = (wn + f*16 + lr)*128 + ((lg ^ lr7)*16);
  }

  f32x4 zero = {0.f, 0.f, 0.f, 0.f};
  f32x4 acc[4][4];
  #pragma unroll
  for (int i = 0; i < 4; ++i)
    #pragma unroll
    for (int j = 0; j < 4; ++j) acc[i][j] = zero;

  for (int k0 = 0; k0 < K; k0 += 32) {
    #pragma unroll
    for (int i = 0; i < 4; ++i) {
      int s = tid + 256*i;
      gload_lds16(asrc[i], (char*)As + (size_t)s*16);
      gload_lds16(bsrc[i], (char*)Bs + (size_t)s*16);
      asrc[i] += 32; bsrc[i] += 32;
    }
    __syncthreads();
    short8 ahf[4], alf[4];
    #pragma unroll
    for (int mf = 0; mf < 4; ++mf) {
      ahf[mf] = *(const short8*)((const char*)As + aoh[mf]);
      alf[mf] = *(const short8*)((const char*)As + (aoh[mf] ^ 64));
    }
    #pragma unroll
    for (int nf = 0; nf < 4; ++nf) {
      short8 bhf = *(const short8*)((const char*)Bs + boh[nf]);
      short8 blf = *(const short8*)((const char*)Bs + (boh[nf] ^ 64));
      #pragma unroll
      for (int mf = 0; mf < 4; ++mf) {
        acc[mf][nf] = mfma16(ahf[mf], bhf, acc[mf][nf]);
        acc[mf][nf] = mfma16(ahf[mf], blf, acc[mf][nf]);
        acc[mf][nf] = mfma16(alf[mf], bhf, acc[mf][nf]);
      }
    }
    __syncthreads();
  }
  #pragma unroll
  for (int nf = 0; nf < 4; ++nf) {
    int col = bn + wn + nf*16 + lr;
    float bv = bias[col];
    #pragma unroll
    for (int mf = 0; mf < 4; ++mf) {
      #pragma unroll
      for (int r = 0; r < 4; ++r) {
        int rowm = bm + wm + mf*16 + lg*4 + r;
        float v = acc[mf][nf][r] + bv;
        if (MODE == 1) {
          fout[(size_t)rowm*N + col] = v;
        } else {
          int sec = col >> 10;          // 0=q 1=k 2=v
          int hh  = (col >> 6) & 15;
          int d   = col & 63;
          int b   = rowm >> 11, t = rowm & 2047;
          size_t bhh = (size_t)b*NH + hh;
          if (sec == 0) v *= 0.125f;    // fold 1/sqrt(HD) into Q
          uint32_t bt = __float_as_uint(v);
          unsigned short h16 = (unsigned short)(bt >> 16);
          unsigned short l16 = rne16(v - __uint_as_float(bt & 0xffff0000u));
          if (sec == 0)      { size_t o = (bhh*T_ + t)*HD + d;  qh[o] = h16;  ql[o] = l16; }
          else if (sec == 1) { size_t o = (bhh*T_ + t)*HD + d;  kh[o] = h16;  kl[o] = l16; }
          else               { size_t o = (bhh*HD + d)*T_ + t;  vth[o] = h16; vtl[o] = l16; }
        }
      }
    }
  }
}

// ---------------- flash attention (causal), swapped-operand form ----------------
// grid 1024. b -> xcd=b&7 (bh group, L2), co-resident qt set {j,15-j,16+j,31-j}
// (constant per-CU work). 4 waves x 16 q rows (QBLK=64), KV tiles of 32,
// double-buffered, one barrier/tile. S^T = mfma(K,Q): lane (lr,lg) holds
// S[q=q0w+lr][kv=kv0+fc*16+lg*4+r] -> per-lane scalar m/l. P redistributed
// in-register (cvt_pk + 8 shfl + select) to the PV B-operand layout.
// O^T = mfma(V^T,P^T): lane holds O[q=q0w+lr][d=df*16+lg*4+r].

__global__ __launch_bounds__(256, 4) void attn_kernel(
    const unsigned short* __restrict__ qh, const unsigned short* __restrict__ ql,
    const unsigned short* __restrict__ kh, const unsigned short* __restrict__ kl,
    const unsigned short* __restrict__ vth, const unsigned short* __restrict__ vtl,
    unsigned short* __restrict__ ctxh, unsigned short* __restrict__ ctxl) {
  __shared__ unsigned short Kt[2][32*128];  // 32 kv-rows x (hi128B|lo128B) = 8KB each
  __shared__ unsigned short Vt[2][64*64];   // 64 d-rows x (hi64B|lo64B)   = 8KB each
  int b = blockIdx.x;
  int xcd = b & 7, bh_lo = (b >> 3) & 3, jj = (b >> 5) & 7, kk = b >> 8;
  int bh = xcd*4 + bh_lo;
  int qt = (kk == 0) ? jj : (kk == 1) ? 15 - jj : (kk == 2) ? 16 + jj : 31 - jj;
  int q0 = qt * 64;
  int tid = threadIdx.x;
  int w = tid >> 6, l = tid & 63, lg = l >> 4, lr = l & 15;
  int q0w = q0 + w*16;
  int qrow = q0w + lr;

  // Q B-frags (col=q=lr, k=d=lg*8+j+32ks); Q pre-scaled by 0.125
  const unsigned short* qbh = qh + ((size_t)bh*T_ + qrow)*HD;
  const unsigned short* qbl = ql + ((size_t)bh*T_ + qrow)*HD;
  short8 qfh[2], qfl[2];
  #pragma unroll
  for (int ks = 0; ks < 2; ++ks) {
    qfh[ks] = *(const short8*)(qbh + ks*32 + lg*8);
    qfl[ks] = *(const short8*)(qbl + ks*32 + lg*8);
  }

  // staging sources: K 512 slots (32 rows x 16 gran), V 512 slots (64 rows x 8 gran)
  const unsigned short* ksrc[2]; const unsigned short* vsrc[2];
  #pragma unroll
  for (int i = 0; i < 2; ++i) {
    int s = tid + 256*i;
    { int r = s >> 4, p = s & 15, u = (p & 8) | ((p & 7) ^ (r & 7));
      ksrc[i] = ((u < 8) ? kh : kl) + ((size_t)bh*T_ + r)*HD + (u & 7)*8; }
    { int r = s >> 3, p = s & 7, u = p ^ (r & 7);
      vsrc[i] = ((u < 4) ? vth : vtl) + ((size_t)bh*HD + r)*T_ + (u & 3)*8; }
  }
  auto stage = [&](int buf) {
    #pragma unroll
    for (int i = 0; i < 2; ++i) {
      int s = tid + 256*i;
      gload_lds16(ksrc[i], (char*)&Kt[buf][0] + (size_t)s*16);
      gload_lds16(vsrc[i], (char*)&Vt[buf][0] + (size_t)s*16);
      ksrc[i] += 32*HD;     // next 32 kv rows
      vsrc[i] += 32;        // next 32 kv cols
    }
  };

  // K A-frag offsets: row=kv=fc*16+lr, k=d=ks*32+lg*8+j ; lo = +128
  int koff[2][2];
  #pragma unroll
  for (int fc = 0; fc < 2; ++fc)
    #pragma unroll
    for (int ks = 0; ks < 2; ++ks) {
      int row = fc*16 + lr;
      koff[fc][ks] = row*256 + (((ks*4 + lg) ^ (row & 7))*16);
    }
  // V A-frag offsets: row=d=df*16+lr, k=kv=lg*8+j ; lo = ^64
  int voff[4];
  #pragma unroll
  for (int df = 0; df < 4; ++df) {
    int row = df*16 + lr;
    voff[df] = row*128 + ((lg ^ (row & 7))*16);
  }

  f32x4 zero = {0.f, 0.f, 0.f, 0.f};
  f32x4 o[4] = {zero, zero, zero, zero};
  float m_r = -1e30f, l_r = 0.f;

  int nkt = 2*qt + 2;
  stage(0);
  __syncthreads();
  int cur = 0;

  // shfl source lanes for P^T redistribution
  int sl = lr + ((lg & 1) << 5);
  int sh = sl + 16;
  bool lglo = lg < 2;

  for (int kt = 0; kt < nkt; ++kt) {
    int kv0 = kt*32;
    if (kt + 1 < nkt) stage(cur ^ 1);
    if (kv0 <= q0w + 15) {                    // wave has live rows in this tile
      const char* KB = (const char*)&Kt[cur][0];
      const char* VB = (const char*)&Vt[cur][0];
      // S^T = K * Q^T   (lane: q=qrow, kv=kv0+fc*16+lg*4+r)
      f32x4 st[2];
      #pragma unroll
      for (int fc = 0; fc < 2; ++fc) {
        f32x4 acc = zero;
        #pragma unroll
        for (int ks = 0; ks < 2; ++ks) {
          short8 khf = *(const short8*)(KB + koff[fc][ks]);
          short8 klf = *(const short8*)(KB + koff[fc][ks] + 128);
          acc = mfma16(khf, qfh[ks], acc);
          acc = mfma16(khf, qfl[ks], acc);
          acc = mfma16(klf, qfh[ks], acc);
        }
        st[fc] = acc;
      }
      if (kv0 + 31 > q0w) {                   // diagonal: elementwise causal mask
        #pragma unroll
        for (int fc = 0; fc < 2; ++fc)
          #pragma unroll
          for (int r = 0; r < 4; ++r) {
            int kv = kv0 + fc*16 + lg*4 + r;
            if (kv > qrow) st[fc][r] = -1e30f;
          }
      }
      // online softmax: per-lane scalar row state
      float pm = fmaxf(fmaxf(fmaxf(st[0][0], st[0][1]), fmaxf(st[0][2], st[0][3])),
                       fmaxf(fmaxf(st[1][0], st[1][1]), fmaxf(st[1][2], st[1][3])));
      pm = fmaxf(pm, __shfl_xor(pm, 16));
      pm = fmaxf(pm, __shfl_xor(pm, 32));
      if (__any(pm > m_r + 8.f)) {            // defer-max (THR=8)
        float mn = fmaxf(m_r, pm);
        float sc = __expf(m_r - mn);
        m_r = mn; l_r *= sc;
        #pragma unroll
        for (int df = 0; df < 4; ++df)
          #pragma unroll
          for (int r = 0; r < 4; ++r) o[df][r] *= sc;
      }
      float sum = 0.f;
      #pragma unroll
      for (int fc = 0; fc < 2; ++fc)
        #pragma unroll
        for (int r = 0; r < 4; ++r) {
          float p = __expf(st[fc][r] - m_r);
          st[fc][r] = p;
          sum += p;
        }
      sum += __shfl_xor(sum, 16);
      sum += __shfl_xor(sum, 32);
      l_r += sum;
      // pack P pairs (hi RNE, lo residual)
      uint32_t Hpk[2][2], Lpk[2][2];
      #pragma unroll
      for (int fc = 0; fc < 2; ++fc)
        #pragma unroll
        for (int i = 0; i < 2; ++i) {
          float pe = st[fc][2*i], po = st[fc][2*i + 1];
          uint32_t H = cvtpk_bf16(pe, po);
          Hpk[fc][i] = H;
          float fe = __uint_as_float(H << 16);
          float fo = __uint_as_float(H & 0xffff0000u);
          Lpk[fc][i] = cvtpk_bf16(pe - fe, po - fo);
        }
      // redistribute to PV B-operand layout (col=q=lr, k=kv=lg*8+j)
      union { u32x4 u; short8 s; } BH, BL;
      {
        int a0 = __shfl((int)Hpk[0][0], sl), b0 = __shfl((int)Hpk[1][0], sl);
        int a1 = __shfl((int)Hpk[0][1], sl), b1 = __shfl((int)Hpk[1][1], sl);
        int a2 = __shfl((int)Hpk[0][0], sh), b2 = __shfl((int)Hpk[1][0], sh);
        int a3 = __shfl((int)Hpk[0][1], sh), b3 = __shfl((int)Hpk[1][1], sh);
        BH.u[0] = lglo ? a0 : b0; BH.u[1] = lglo ? a1 : b1;
        BH.u[2] = lglo ? a2 : b2; BH.u[3] = lglo ? a3 : b3;
      }
      {
        int a0 = __shfl((int)Lpk[0][0], sl), b0 = __shfl((int)Lpk[1][0], sl);
        int a1 = __shfl((int)Lpk[0][1], sl), b1 = __shfl((int)Lpk[1][1], sl);
        int a2 = __shfl((int)Lpk[0][0], sh), b2 = __shfl((int)Lpk[1][0], sh);
        int a3 = __shfl((int)Lpk[0][1], sh), b3 = __shfl((int)Lpk[1][1], sh);
        BL.u[0] = lglo ? a0 : b0; BL.u[1] = lglo ? a1 : b1;
        BL.u[2] = lglo ? a2 : b2; BL.u[3] = lglo ? a3 : b3;
      }
      // O^T += V^T * P^T
      #pragma unroll
      for (int df = 0; df < 4; ++df) {
        short8 vhf = *(const short8*)(VB + voff[df]);
        short8 vlf = *(const short8*)(VB + (voff[df] ^ 64));
        o[df] = mfma16(vhf, BH.s, o[df]);
        o[df] = mfma16(vhf, BL.s, o[df]);
        o[df] = mfma16(vlf, BH.s, o[df]);
      }
    }
    __syncthreads();
    cur ^= 1;
  }
  // epilogue: lane holds O[q=qrow][d=df*16+lg*4+r]; ctx planes [b][t][h*64+d]
  int bb = bh >> 4, h = bh & 15;
  float inv = 1.0f / l_r;
  #pragma unroll
  for (int df = 0; df < 4; ++df) {
    ushort4 hv, lv;
    unsigned short hh[4], ll[4];
    #pragma unroll
    for (int r = 0; r < 4; ++r) {
      float v = o[df][r] * inv;
      uint32_t bt = __float_as_uint(v);
      hh[r] = (unsigned short)(bt >> 16);
      ll[r] = rne16(v - __uint_as_float(bt & 0xffff0000u));
    }
    hv.x=hh[0]; hv.y=hh[1]; hv.z=hh[2]; hv.w=hh[3];
    lv.x=ll[0]; lv.y=ll[1]; lv.z=ll[2]; lv.w=ll[3];
    size_t oo = ((size_t)bb*T_ + qrow)*C_ + h*HD + df*16 + lg*4;
    *(ushort4*)&ctxh[oo] = hv;
    *(ushort4*)&ctxl[oo] = lv;
  }
}

// ---------------- launch ----------------

extern "C" void kernel_launch(void* const* d_in, const int* in_sizes, int n_in,
                              void* d_out, int out_size, void* d_ws, size_t ws_size,
                              hipStream_t stream) {
  (void)in_sizes; (void)n_in; (void)out_size; (void)ws_size;
  const float* x      = (const float*)d_in[0];
  const float* w_qkv  = (const float*)d_in[1];
  const float* b_qkv  = (const float*)d_in[2];
  const float* w_proj = (const float*)d_in[3];
  const float* b_proj = (const float*)d_in[4];
  float* out = (float*)d_out;

  uint8_t* ws = (uint8_t*)d_ws;
  const size_t MB = (size_t)1 << 20;
  unsigned short* xh  = (unsigned short*)(ws + 0);      // 8MB  [M][C] hi
  unsigned short* xl  = (unsigned short*)(ws + 8*MB);   // 8MB  lo
  unsigned short* cth = xh;                             // ctx aliases x (dead)
  unsigned short* ctl = xl;
  unsigned short* wqh = (unsigned short*)(ws + 16*MB);  // 6MB  w_qkv^T hi [3C][C]
  unsigned short* wql = (unsigned short*)(ws + 22*MB);  // 6MB
  unsigned short* wph = (unsigned short*)(ws + 28*MB);  // 2MB  w_proj^T hi [C][C]
  unsigned short* wpl = (unsigned short*)(ws + 30*MB);  // 2MB
  unsigned short* qhp = (unsigned short*)(ws + 32*MB);  // 8MB  Q hi [BH][T][HD] (x0.125)
  unsigned short* qlp = (unsigned short*)(ws + 40*MB);  // 8MB
  unsigned short* khp = (unsigned short*)(ws + 48*MB);  // 8MB  K hi
  unsigned short* klp = (unsigned short*)(ws + 56*MB);  // 8MB
  unsigned short* vth = (unsigned short*)(ws + 64*MB);  // 8MB  V^T hi [BH][HD][T]
  unsigned short* vtl = (unsigned short*)(ws + 72*MB);  // 8MB   -> 80MB total

  pack4_kernel<<<(M_*C_/4 + 255)/256, 256, 0, stream>>>((const float4*)x, xh, xl, M_*C_/4);
  pack_t_kernel<<<dim3(3*C_/64, C_/64), dim3(64, 16), 0, stream>>>(w_qkv, wqh, wql, C_, 3*C_);
  pack_t_kernel<<<dim3(C_/64, C_/64), dim3(64, 16), 0, stream>>>(w_proj, wph, wpl, C_, C_);
  gemm_planes<0><<<dim3(3*C_/128, M_/128), 256, 0, stream>>>(
      xh, xl, wqh, wql, b_qkv, qhp, qlp, khp, klp, vth, vtl, nullptr, M_, 3*C_, C_);
  attn_kernel<<<dim3(1024), 256, 0, stream>>>(qhp, qlp, khp, klp, vth, vtl, cth, ctl);
  gemm_planes<1><<<dim3(C_/128, M_/128), 256, 0, stream>>>(
      cth, ctl, wph, wpl, b_proj, nullptr, nullptr, nullptr, nullptr, nullptr, nullptr,
      out, M_, C_, C_);
}

// Round 10
// 345.978 us; speedup vs baseline: 1.1934x; 1.0267x over previous
//
#include <hip/hip_runtime.h>
#include <stdint.h>

// MultiHeadSelfAttention: B=2 T=2048 C=1024 H=16 D=64, fp32 in/out.
// Split-precision bf16x3 MFMA (x = hi+lo bf16; a*b ~= ah*bh + ah*bl + al*bh).
// R10: gemm_planes upgraded 1-phase -> 2-phase: double-buffered LDS (64KB),
// prefetch next K-tile issued BEFORE computing current, ONE barrier per K-step
// (was: stage -> barrier(vmcnt0 drain exposed) -> compute -> barrier).
// Attention (swapped-operand, R4) and packs unchanged — R9 measured gemm<0>
// as the top dispatch (139us, MfmaUtil 23%, 55% stall).

#define B_  2
#define T_  2048
#define C_  1024
#define NH  16
#define HD  64
#define BH_ (B_*NH)   // 32
#define M_  (B_*T_)   // 4096

typedef __attribute__((ext_vector_type(8))) short short8;
typedef __attribute__((ext_vector_type(4))) float f32x4;
typedef __attribute__((ext_vector_type(4))) uint32_t u32x4;

typedef const __attribute__((address_space(1))) void* gas_ptr;
typedef __attribute__((address_space(3))) void* las_ptr;

__device__ __forceinline__ void gload_lds16(const void* g, void* l) {
  __builtin_amdgcn_global_load_lds((gas_ptr)g, (las_ptr)l, 16, 0, 0);
}

__device__ __forceinline__ unsigned short rne16(float x){
  uint32_t v = __float_as_uint(x);
  return (unsigned short)((v + 0x7fffu + ((v >> 16) & 1u)) >> 16);
}

__device__ __forceinline__ uint32_t cvtpk_bf16(float a, float b){
  uint32_t r;
  asm("v_cvt_pk_bf16_f32 %0, %1, %2" : "=v"(r) : "v"(a), "v"(b));
  return r;   // low16 = bf16(a), high16 = bf16(b)
}

__device__ __forceinline__ f32x4 mfma16(short8 a, short8 b, f32x4 c) {
  return __builtin_amdgcn_mfma_f32_16x16x32_bf16(a, b, c, 0, 0, 0);
}

// ---------------- pack kernels (unchanged) ----------------

__global__ __launch_bounds__(256) void pack4_kernel(const float4* __restrict__ in,
                                                    unsigned short* __restrict__ oh,
                                                    unsigned short* __restrict__ ol, int n4) {
  int i = blockIdx.x * 256 + threadIdx.x;
  if (i < n4) {
    float4 v = in[i];
    float f[4] = {v.x, v.y, v.z, v.w};
    ushort4 h, lo;
    unsigned short hh[4], ll[4];
    #pragma unroll
    for (int j=0;j<4;++j){
      uint32_t bt = __float_as_uint(f[j]);
      hh[j] = (unsigned short)(bt >> 16);
      ll[j] = rne16(f[j] - __uint_as_float(bt & 0xffff0000u));
    }
    h.x=hh[0]; h.y=hh[1]; h.z=hh[2]; h.w=hh[3];
    lo.x=ll[0]; lo.y=ll[1]; lo.z=ll[2]; lo.w=ll[3];
    *(ushort4*)(oh + (size_t)i*4) = h;
    *(ushort4*)(ol + (size_t)i*4) = lo;
  }
}

__global__ __launch_bounds__(1024) void pack_t_kernel(const float* __restrict__ in,
                                                      unsigned short* __restrict__ oh,
                                                      unsigned short* __restrict__ ol,
                                                      int R, int C) {
  __shared__ float tile[64][65];
  int c0 = blockIdx.x * 64, r0 = blockIdx.y * 64;
  int tx = threadIdx.x, ty = threadIdx.y;
  #pragma unroll
  for (int i = 0; i < 4; ++i)
    tile[ty + 16*i][tx] = in[(size_t)(r0 + ty + 16*i)*C + c0 + tx];
  __syncthreads();
  #pragma unroll
  for (int i = 0; i < 4; ++i) {
    float v = tile[tx][ty + 16*i];
    uint32_t bt = __float_as_uint(v);
    size_t o = (size_t)(c0 + ty + 16*i)*R + r0 + tx;
    oh[o] = (unsigned short)(bt >> 16);
    ol[o] = rne16(v - __uint_as_float(bt & 0xffff0000u));
  }
}

// ---------------- GEMM (128x128 tile, BK=32, 4 waves, hi/lo planes) ----------------
// R10: 2-phase double-buffered. Per K-step: issue stage(next buf) -> ds_read +
// 48 MFMA on cur buf -> one __syncthreads (drains prefetch, protects flip).
// LDS row r = [hi 64B | lo 64B] = 8 granules of 16B, granule position = u ^ (r&7).
// MODE 0: qkv epilogue (scatter Q(scaled)/K/Vt hi-lo planes + bias); MODE 1: fp32 out.

template<int MODE>
__global__ __launch_bounds__(256) void gemm_planes(
    const unsigned short* __restrict__ Ah, const unsigned short* __restrict__ Al,
    const unsigned short* __restrict__ Bh, const unsigned short* __restrict__ Bl,
    const float* __restrict__ bias,
    unsigned short* __restrict__ qh, unsigned short* __restrict__ ql,
    unsigned short* __restrict__ kh, unsigned short* __restrict__ kl,
    unsigned short* __restrict__ vth, unsigned short* __restrict__ vtl,
    float* __restrict__ fout, int M, int N, int K) {
  __shared__ unsigned short As[2][128*64];   // 2 x 16KB
  __shared__ unsigned short Bs[2][128*64];   // 2 x 16KB  -> 64KB total
  int tid = threadIdx.x;
  int w = tid >> 6, l = tid & 63, lg = l >> 4, lr = l & 15, lr7 = lr & 7;
  int bm = blockIdx.y * 128, bn = blockIdx.x * 128;
  int wm = (w >> 1) * 64, wn = (w & 1) * 64;

  // staging sources (pre-swizzled: LDS slot s -> plane granule u = (s&7)^(row&7))
  const unsigned short* asrc[4]; const unsigned short* bsrc[4];
  #pragma unroll
  for (int i = 0; i < 4; ++i) {
    int s = tid + 256*i; int r = s >> 3, p = s & 7, u = p ^ (r & 7);
    asrc[i] = ((u < 4) ? Ah : Al) + (size_t)(bm + r)*K + (u & 3)*8;
    bsrc[i] = ((u < 4) ? Bh : Bl) + (size_t)(bn + r)*K + (u & 3)*8;
  }
  auto stage = [&](int buf) {
    #pragma unroll
    for (int i = 0; i < 4; ++i) {
      int s = tid + 256*i;
      gload_lds16(asrc[i], (char*)&As[buf][0] + (size_t)s*16);
      gload_lds16(bsrc[i], (char*)&Bs[buf][0] + (size_t)s*16);
      asrc[i] += 32; bsrc[i] += 32;
    }
  };
  // fragment read byte-offsets within a buffer (hi; lo = ^64)
  int aoh[4], boh[4];
  #pragma unroll
  for (int f = 0; f < 4; ++f) {
    aoh[f] = (wm + f*16 + lr)*128 + ((lg ^ lr7)*16);
    boh[f] = (wn + f*16 + lr)*128 + ((lg ^ lr7)*16);
  }

  f32x4 zero = {0.f, 0.f, 0.f, 0.f};
  f32x4 acc[4][4];
  #pragma unroll
  for (int i = 0; i < 4; ++i)
    #pragma unroll
    for (int j = 0; j < 4; ++j) acc[i][j] = zero;

  stage(0);
  __syncthreads();
  int cur = 0;
  int nk = K >> 5;
  for (int t = 0; t < nk; ++t) {
    if (t + 1 < nk) stage(cur ^ 1);          // prefetch next K-tile (no wait)
    const char* AB = (const char*)&As[cur][0];
    const char* BB = (const char*)&Bs[cur][0];
    short8 ahf[4], alf[4];
    #pragma unroll
    for (int mf = 0; mf < 4; ++mf) {
      ahf[mf] = *(const short8*)(AB + aoh[mf]);
      alf[mf] = *(const short8*)(AB + (aoh[mf] ^ 64));
    }
    #pragma unroll
    for (int nf = 0; nf < 4; ++nf) {
      short8 bhf = *(const short8*)(BB + boh[nf]);
      short8 blf = *(const short8*)(BB + (boh[nf] ^ 64));
      #pragma unroll
      for (int mf = 0; mf < 4; ++mf) {
        acc[mf][nf] = mfma16(ahf[mf], bhf, acc[mf][nf]);
        acc[mf][nf] = mfma16(ahf[mf], blf, acc[mf][nf]);
        acc[mf][nf] = mfma16(alf[mf], bhf, acc[mf][nf]);
      }
    }
    __syncthreads();                         // prefetch landed + cur reads done
    cur ^= 1;
  }
  // epilogue: D row = lg*4+r, col = lr (m89 layout)
  #pragma unroll
  for (int nf = 0; nf < 4; ++nf) {
    int col = bn + wn + nf*16 + lr;
    float bv = bias[col];
    #pragma unroll
    for (int mf = 0; mf < 4; ++mf) {
      #pragma unroll
      for (int r = 0; r < 4; ++r) {
        int rowm = bm + wm + mf*16 + lg*4 + r;
        float v = acc[mf][nf][r] + bv;
        if (MODE == 1) {
          fout[(size_t)rowm*N + col] = v;
        } else {
          int sec = col >> 10;          // 0=q 1=k 2=v
          int hh  = (col >> 6) & 15;
          int d   = col & 63;
          int b   = rowm >> 11, t = rowm & 2047;
          size_t bhh = (size_t)b*NH + hh;
          if (sec == 0) v *= 0.125f;    // fold 1/sqrt(HD) into Q
          uint32_t bt = __float_as_uint(v);
          unsigned short h16 = (unsigned short)(bt >> 16);
          unsigned short l16 = rne16(v - __uint_as_float(bt & 0xffff0000u));
          if (sec == 0)      { size_t o = (bhh*T_ + t)*HD + d;  qh[o] = h16;  ql[o] = l16; }
          else if (sec == 1) { size_t o = (bhh*T_ + t)*HD + d;  kh[o] = h16;  kl[o] = l16; }
          else               { size_t o = (bhh*HD + d)*T_ + t;  vth[o] = h16; vtl[o] = l16; }
        }
      }
    }
  }
}

// ---------------- flash attention (causal), swapped-operand form (unchanged) ----------------
// grid 1024. b -> xcd=b&7 (bh group, L2), co-resident qt set {j,15-j,16+j,31-j}
// (constant per-CU work). 4 waves x 16 q rows (QBLK=64), KV tiles of 32,
// double-buffered, one barrier/tile. S^T = mfma(K,Q): lane (lr,lg) holds
// S[q=q0w+lr][kv=kv0+fc*16+lg*4+r] -> per-lane scalar m/l. P redistributed
// in-register (cvt_pk + 8 shfl + select) to the PV B-operand layout.
// O^T = mfma(V^T,P^T): lane holds O[q=q0w+lr][d=df*16+lg*4+r].

__global__ __launch_bounds__(256, 4) void attn_kernel(
    const unsigned short* __restrict__ qh, const unsigned short* __restrict__ ql,
    const unsigned short* __restrict__ kh, const unsigned short* __restrict__ kl,
    const unsigned short* __restrict__ vth, const unsigned short* __restrict__ vtl,
    unsigned short* __restrict__ ctxh, unsigned short* __restrict__ ctxl) {
  __shared__ unsigned short Kt[2][32*128];  // 32 kv-rows x (hi128B|lo128B) = 8KB each
  __shared__ unsigned short Vt[2][64*64];   // 64 d-rows x (hi64B|lo64B)   = 8KB each
  int b = blockIdx.x;
  int xcd = b & 7, bh_lo = (b >> 3) & 3, jj = (b >> 5) & 7, kk = b >> 8;
  int bh = xcd*4 + bh_lo;
  int qt = (kk == 0) ? jj : (kk == 1) ? 15 - jj : (kk == 2) ? 16 + jj : 31 - jj;
  int q0 = qt * 64;
  int tid = threadIdx.x;
  int w = tid >> 6, l = tid & 63, lg = l >> 4, lr = l & 15;
  int q0w = q0 + w*16;
  int qrow = q0w + lr;

  // Q B-frags (col=q=lr, k=d=lg*8+j+32ks); Q pre-scaled by 0.125
  const unsigned short* qbh = qh + ((size_t)bh*T_ + qrow)*HD;
  const unsigned short* qbl = ql + ((size_t)bh*T_ + qrow)*HD;
  short8 qfh[2], qfl[2];
  #pragma unroll
  for (int ks = 0; ks < 2; ++ks) {
    qfh[ks] = *(const short8*)(qbh + ks*32 + lg*8);
    qfl[ks] = *(const short8*)(qbl + ks*32 + lg*8);
  }

  // staging sources: K 512 slots (32 rows x 16 gran), V 512 slots (64 rows x 8 gran)
  const unsigned short* ksrc[2]; const unsigned short* vsrc[2];
  #pragma unroll
  for (int i = 0; i < 2; ++i) {
    int s = tid + 256*i;
    { int r = s >> 4, p = s & 15, u = (p & 8) | ((p & 7) ^ (r & 7));
      ksrc[i] = ((u < 8) ? kh : kl) + ((size_t)bh*T_ + r)*HD + (u & 7)*8; }
    { int r = s >> 3, p = s & 7, u = p ^ (r & 7);
      vsrc[i] = ((u < 4) ? vth : vtl) + ((size_t)bh*HD + r)*T_ + (u & 3)*8; }
  }
  auto stage = [&](int buf) {
    #pragma unroll
    for (int i = 0; i < 2; ++i) {
      int s = tid + 256*i;
      gload_lds16(ksrc[i], (char*)&Kt[buf][0] + (size_t)s*16);
      gload_lds16(vsrc[i], (char*)&Vt[buf][0] + (size_t)s*16);
      ksrc[i] += 32*HD;     // next 32 kv rows
      vsrc[i] += 32;        // next 32 kv cols
    }
  };

  // K A-frag offsets: row=kv=fc*16+lr, k=d=ks*32+lg*8+j ; lo = +128
  int koff[2][2];
  #pragma unroll
  for (int fc = 0; fc < 2; ++fc)
    #pragma unroll
    for (int ks = 0; ks < 2; ++ks) {
      int row = fc*16 + lr;
      koff[fc][ks] = row*256 + (((ks*4 + lg) ^ (row & 7))*16);
    }
  // V A-frag offsets: row=d=df*16+lr, k=kv=lg*8+j ; lo = ^64
  int voff[4];
  #pragma unroll
  for (int df = 0; df < 4; ++df) {
    int row = df*16 + lr;
    voff[df] = row*128 + ((lg ^ (row & 7))*16);
  }

  f32x4 zero = {0.f, 0.f, 0.f, 0.f};
  f32x4 o[4] = {zero, zero, zero, zero};
  float m_r = -1e30f, l_r = 0.f;

  int nkt = 2*qt + 2;
  stage(0);
  __syncthreads();
  int cur = 0;

  // shfl source lanes for P^T redistribution
  int sl = lr + ((lg & 1) << 5);
  int sh = sl + 16;
  bool lglo = lg < 2;

  for (int kt = 0; kt < nkt; ++kt) {
    int kv0 = kt*32;
    if (kt + 1 < nkt) stage(cur ^ 1);
    if (kv0 <= q0w + 15) {                    // wave has live rows in this tile
      const char* KB = (const char*)&Kt[cur][0];
      const char* VB = (const char*)&Vt[cur][0];
      // S^T = K * Q^T   (lane: q=qrow, kv=kv0+fc*16+lg*4+r)
      f32x4 st[2];
      #pragma unroll
      for (int fc = 0; fc < 2; ++fc) {
        f32x4 acc = zero;
        #pragma unroll
        for (int ks = 0; ks < 2; ++ks) {
          short8 khf = *(const short8*)(KB + koff[fc][ks]);
          short8 klf = *(const short8*)(KB + koff[fc][ks] + 128);
          acc = mfma16(khf, qfh[ks], acc);
          acc = mfma16(khf, qfl[ks], acc);
          acc = mfma16(klf, qfh[ks], acc);
        }
        st[fc] = acc;
      }
      if (kv0 + 31 > q0w) {                   // diagonal: elementwise causal mask
        #pragma unroll
        for (int fc = 0; fc < 2; ++fc)
          #pragma unroll
          for (int r = 0; r < 4; ++r) {
            int kv = kv0 + fc*16 + lg*4 + r;
            if (kv > qrow) st[fc][r] = -1e30f;
          }
      }
      // online softmax: per-lane scalar row state
      float pm = fmaxf(fmaxf(fmaxf(st[0][0], st[0][1]), fmaxf(st[0][2], st[0][3])),
                       fmaxf(fmaxf(st[1][0], st[1][1]), fmaxf(st[1][2], st[1][3])));
      pm = fmaxf(pm, __shfl_xor(pm, 16));
      pm = fmaxf(pm, __shfl_xor(pm, 32));
      if (__any(pm > m_r + 8.f)) {            // defer-max (THR=8)
        float mn = fmaxf(m_r, pm);
        float sc = __expf(m_r - mn);
        m_r = mn; l_r *= sc;
        #pragma unroll
        for (int df = 0; df < 4; ++df)
          #pragma unroll
          for (int r = 0; r < 4; ++r) o[df][r] *= sc;
      }
      float sum = 0.f;
      #pragma unroll
      for (int fc = 0; fc < 2; ++fc)
        #pragma unroll
        for (int r = 0; r < 4; ++r) {
          float p = __expf(st[fc][r] - m_r);
          st[fc][r] = p;
          sum += p;
        }
      sum += __shfl_xor(sum, 16);
      sum += __shfl_xor(sum, 32);
      l_r += sum;
      // pack P pairs (hi RNE, lo residual)
      uint32_t Hpk[2][2], Lpk[2][2];
      #pragma unroll
      for (int fc = 0; fc < 2; ++fc)
        #pragma unroll
        for (int i = 0; i < 2; ++i) {
          float pe = st[fc][2*i], po = st[fc][2*i + 1];
          uint32_t H = cvtpk_bf16(pe, po);
          Hpk[fc][i] = H;
          float fe = __uint_as_float(H << 16);
          float fo = __uint_as_float(H & 0xffff0000u);
          Lpk[fc][i] = cvtpk_bf16(pe - fe, po - fo);
        }
      // redistribute to PV B-operand layout (col=q=lr, k=kv=lg*8+j)
      union { u32x4 u; short8 s; } BH, BL;
      {
        int a0 = __shfl((int)Hpk[0][0], sl), b0 = __shfl((int)Hpk[1][0], sl);
        int a1 = __shfl((int)Hpk[0][1], sl), b1 = __shfl((int)Hpk[1][1], sl);
        int a2 = __shfl((int)Hpk[0][0], sh), b2 = __shfl((int)Hpk[1][0], sh);
        int a3 = __shfl((int)Hpk[0][1], sh), b3 = __shfl((int)Hpk[1][1], sh);
        BH.u[0] = lglo ? a0 : b0; BH.u[1] = lglo ? a1 : b1;
        BH.u[2] = lglo ? a2 : b2; BH.u[3] = lglo ? a3 : b3;
      }
      {
        int a0 = __shfl((int)Lpk[0][0], sl), b0 = __shfl((int)Lpk[1][0], sl);
        int a1 = __shfl((int)Lpk[0][1], sl), b1 = __shfl((int)Lpk[1][1], sl);
        int a2 = __shfl((int)Lpk[0][0], sh), b2 = __shfl((int)Lpk[1][0], sh);
        int a3 = __shfl((int)Lpk[0][1], sh), b3 = __shfl((int)Lpk[1][1], sh);
        BL.u[0] = lglo ? a0 : b0; BL.u[1] = lglo ? a1 : b1;
        BL.u[2] = lglo ? a2 : b2; BL.u[3] = lglo ? a3 : b3;
      }
      // O^T += V^T * P^T
      #pragma unroll
      for (int df = 0; df < 4; ++df) {
        short8 vhf = *(const short8*)(VB + voff[df]);
        short8 vlf = *(const short8*)(VB + (voff[df] ^ 64));
        o[df] = mfma16(vhf, BH.s, o[df]);
        o[df] = mfma16(vhf, BL.s, o[df]);
        o[df] = mfma16(vlf, BH.s, o[df]);
      }
    }
    __syncthreads();
    cur ^= 1;
  }
  // epilogue: lane holds O[q=qrow][d=df*16+lg*4+r]; ctx planes [b][t][h*64+d]
  int bb = bh >> 4, h = bh & 15;
  float inv = 1.0f / l_r;
  #pragma unroll
  for (int df = 0; df < 4; ++df) {
    ushort4 hv, lv;
    unsigned short hh[4], ll[4];
    #pragma unroll
    for (int r = 0; r < 4; ++r) {
      float v = o[df][r] * inv;
      uint32_t bt = __float_as_uint(v);
      hh[r] = (unsigned short)(bt >> 16);
      ll[r] = rne16(v - __uint_as_float(bt & 0xffff0000u));
    }
    hv.x=hh[0]; hv.y=hh[1]; hv.z=hh[2]; hv.w=hh[3];
    lv.x=ll[0]; lv.y=ll[1]; lv.z=ll[2]; lv.w=ll[3];
    size_t oo = ((size_t)bb*T_ + qrow)*C_ + h*HD + df*16 + lg*4;
    *(ushort4*)&ctxh[oo] = hv;
    *(ushort4*)&ctxl[oo] = lv;
  }
}

// ---------------- launch ----------------

extern "C" void kernel_launch(void* const* d_in, const int* in_sizes, int n_in,
                              void* d_out, int out_size, void* d_ws, size_t ws_size,
                              hipStream_t stream) {
  (void)in_sizes; (void)n_in; (void)out_size; (void)ws_size;
  const float* x      = (const float*)d_in[0];
  const float* w_qkv  = (const float*)d_in[1];
  const float* b_qkv  = (const float*)d_in[2];
  const float* w_proj = (const float*)d_in[3];
  const float* b_proj = (const float*)d_in[4];
  float* out = (float*)d_out;

  uint8_t* ws = (uint8_t*)d_ws;
  const size_t MB = (size_t)1 << 20;
  unsigned short* xh  = (unsigned short*)(ws + 0);      // 8MB  [M][C] hi
  unsigned short* xl  = (unsigned short*)(ws + 8*MB);   // 8MB  lo
  unsigned short* cth = xh;                             // ctx aliases x (dead)
  unsigned short* ctl = xl;
  unsigned short* wqh = (unsigned short*)(ws + 16*MB);  // 6MB  w_qkv^T hi [3C][C]
  unsigned short* wql = (unsigned short*)(ws + 22*MB);  // 6MB
  unsigned short* wph = (unsigned short*)(ws + 28*MB);  // 2MB  w_proj^T hi [C][C]
  unsigned short* wpl = (unsigned short*)(ws + 30*MB);  // 2MB
  unsigned short* qhp = (unsigned short*)(ws + 32*MB);  // 8MB  Q hi [BH][T][HD] (x0.125)
  unsigned short* qlp = (unsigned short*)(ws + 40*MB);  // 8MB
  unsigned short* khp = (unsigned short*)(ws + 48*MB);  // 8MB  K hi
  unsigned short* klp = (unsigned short*)(ws + 56*MB);  // 8MB
  unsigned short* vth = (unsigned short*)(ws + 64*MB);  // 8MB  V^T hi [BH][HD][T]
  unsigned short* vtl = (unsigned short*)(ws + 72*MB);  // 8MB   -> 80MB total

  pack4_kernel<<<(M_*C_/4 + 255)/256, 256, 0, stream>>>((const float4*)x, xh, xl, M_*C_/4);
  pack_t_kernel<<<dim3(3*C_/64, C_/64), dim3(64, 16), 0, stream>>>(w_qkv, wqh, wql, C_, 3*C_);
  pack_t_kernel<<<dim3(C_/64, C_/64), dim3(64, 16), 0, stream>>>(w_proj, wph, wpl, C_, C_);
  gemm_planes<0><<<dim3(3*C_/128, M_/128), 256, 0, stream>>>(
      xh, xl, wqh, wql, b_qkv, qhp, qlp, khp, klp, vth, vtl, nullptr, M_, 3*C_, C_);
  attn_kernel<<<dim3(1024), 256, 0, stream>>>(qhp, qlp, khp, klp, vth, vtl, cth, ctl);
  gemm_planes<1><<<dim3(C_/128, M_/128), 256, 0, stream>>>(
      cth, ctl, wph, wpl, b_proj, nullptr, nullptr, nullptr, nullptr, nullptr, nullptr,
      out, M_, C_, C_);
}

// Round 11
// 345.059 us; speedup vs baseline: 1.1966x; 1.0027x over previous
//
#include <hip/hip_runtime.h>
#include <stdint.h>

// MultiHeadSelfAttention: B=2 T=2048 C=1024 H=16 D=64, fp32 in/out.
// Split-precision bf16x3 MFMA (x = hi+lo bf16; a*b ~= ah*bh + ah*bl + al*bh).
// R11: counted-vmcnt barriers (T4). __syncthreads() in the K-loops drained
// vmcnt(0) -> waited on the *just-issued* prefetch (R10: only +4%). Now:
// s_waitcnt vmcnt(N) lgkmcnt(0) + raw s_barrier, N = loads-in-flight per
// stage (gemm: 8, attn: 4) -> prefetch stays in flight across the barrier,
// we wait only on the previous tile's loads (already landed).
// lgkmcnt(0) closes the WAR hazard (ds_reads done before buffer overwrite).

#define B_  2
#define T_  2048
#define C_  1024
#define NH  16
#define HD  64
#define BH_ (B_*NH)   // 32
#define M_  (B_*T_)   // 4096

typedef __attribute__((ext_vector_type(8))) short short8;
typedef __attribute__((ext_vector_type(4))) float f32x4;
typedef __attribute__((ext_vector_type(4))) uint32_t u32x4;

typedef const __attribute__((address_space(1))) void* gas_ptr;
typedef __attribute__((address_space(3))) void* las_ptr;

__device__ __forceinline__ void gload_lds16(const void* g, void* l) {
  __builtin_amdgcn_global_load_lds((gas_ptr)g, (las_ptr)l, 16, 0, 0);
}

// barrier that keeps the newest N vmem ops in flight (T4). lgkmcnt(0) is
// effectively free (MFMAs consumed the ds_reads) and protects the
// write-after-read on the LDS buffer being flipped.
__device__ __forceinline__ void barrier_inflight8() {
  __builtin_amdgcn_sched_barrier(0);
  asm volatile("s_waitcnt vmcnt(8) lgkmcnt(0)" ::: "memory");
  __builtin_amdgcn_s_barrier();
  __builtin_amdgcn_sched_barrier(0);
}
__device__ __forceinline__ void barrier_inflight4() {
  __builtin_amdgcn_sched_barrier(0);
  asm volatile("s_waitcnt vmcnt(4) lgkmcnt(0)" ::: "memory");
  __builtin_amdgcn_s_barrier();
  __builtin_amdgcn_sched_barrier(0);
}

__device__ __forceinline__ unsigned short rne16(float x){
  uint32_t v = __float_as_uint(x);
  return (unsigned short)((v + 0x7fffu + ((v >> 16) & 1u)) >> 16);
}

__device__ __forceinline__ uint32_t cvtpk_bf16(float a, float b){
  uint32_t r;
  asm("v_cvt_pk_bf16_f32 %0, %1, %2" : "=v"(r) : "v"(a), "v"(b));
  return r;   // low16 = bf16(a), high16 = bf16(b)
}

__device__ __forceinline__ f32x4 mfma16(short8 a, short8 b, f32x4 c) {
  return __builtin_amdgcn_mfma_f32_16x16x32_bf16(a, b, c, 0, 0, 0);
}

// ---------------- pack kernels (unchanged) ----------------

__global__ __launch_bounds__(256) void pack4_kernel(const float4* __restrict__ in,
                                                    unsigned short* __restrict__ oh,
                                                    unsigned short* __restrict__ ol, int n4) {
  int i = blockIdx.x * 256 + threadIdx.x;
  if (i < n4) {
    float4 v = in[i];
    float f[4] = {v.x, v.y, v.z, v.w};
    ushort4 h, lo;
    unsigned short hh[4], ll[4];
    #pragma unroll
    for (int j=0;j<4;++j){
      uint32_t bt = __float_as_uint(f[j]);
      hh[j] = (unsigned short)(bt >> 16);
      ll[j] = rne16(f[j] - __uint_as_float(bt & 0xffff0000u));
    }
    h.x=hh[0]; h.y=hh[1]; h.z=hh[2]; h.w=hh[3];
    lo.x=ll[0]; lo.y=ll[1]; lo.z=ll[2]; lo.w=ll[3];
    *(ushort4*)(oh + (size_t)i*4) = h;
    *(ushort4*)(ol + (size_t)i*4) = lo;
  }
}

__global__ __launch_bounds__(1024) void pack_t_kernel(const float* __restrict__ in,
                                                      unsigned short* __restrict__ oh,
                                                      unsigned short* __restrict__ ol,
                                                      int R, int C) {
  __shared__ float tile[64][65];
  int c0 = blockIdx.x * 64, r0 = blockIdx.y * 64;
  int tx = threadIdx.x, ty = threadIdx.y;
  #pragma unroll
  for (int i = 0; i < 4; ++i)
    tile[ty + 16*i][tx] = in[(size_t)(r0 + ty + 16*i)*C + c0 + tx];
  __syncthreads();
  #pragma unroll
  for (int i = 0; i < 4; ++i) {
    float v = tile[tx][ty + 16*i];
    uint32_t bt = __float_as_uint(v);
    size_t o = (size_t)(c0 + ty + 16*i)*R + r0 + tx;
    oh[o] = (unsigned short)(bt >> 16);
    ol[o] = rne16(v - __uint_as_float(bt & 0xffff0000u));
  }
}

// ---------------- GEMM (128x128 tile, BK=32, 4 waves, hi/lo planes) ----------------
// 2-phase double-buffered + counted-vmcnt barrier (R11). Per K-step:
// issue stage(next buf) [8 gload_lds] -> ds_read + 48 MFMA on cur buf ->
// vmcnt(8) lgkmcnt(0) + s_barrier (prefetch stays in flight).

template<int MODE>
__global__ __launch_bounds__(256) void gemm_planes(
    const unsigned short* __restrict__ Ah, const unsigned short* __restrict__ Al,
    const unsigned short* __restrict__ Bh, const unsigned short* __restrict__ Bl,
    const float* __restrict__ bias,
    unsigned short* __restrict__ qh, unsigned short* __restrict__ ql,
    unsigned short* __restrict__ kh, unsigned short* __restrict__ kl,
    unsigned short* __restrict__ vth, unsigned short* __restrict__ vtl,
    float* __restrict__ fout, int M, int N, int K) {
  __shared__ unsigned short As[2][128*64];   // 2 x 16KB
  __shared__ unsigned short Bs[2][128*64];   // 2 x 16KB  -> 64KB total
  int tid = threadIdx.x;
  int w = tid >> 6, l = tid & 63, lg = l >> 4, lr = l & 15, lr7 = lr & 7;
  int bm = blockIdx.y * 128, bn = blockIdx.x * 128;
  int wm = (w >> 1) * 64, wn = (w & 1) * 64;

  // staging sources (pre-swizzled: LDS slot s -> plane granule u = (s&7)^(row&7))
  const unsigned short* asrc[4]; const unsigned short* bsrc[4];
  #pragma unroll
  for (int i = 0; i < 4; ++i) {
    int s = tid + 256*i; int r = s >> 3, p = s & 7, u = p ^ (r & 7);
    asrc[i] = ((u < 4) ? Ah : Al) + (size_t)(bm + r)*K + (u & 3)*8;
    bsrc[i] = ((u < 4) ? Bh : Bl) + (size_t)(bn + r)*K + (u & 3)*8;
  }
  auto stage = [&](int buf) {
    #pragma unroll
    for (int i = 0; i < 4; ++i) {
      int s = tid + 256*i;
      gload_lds16(asrc[i], (char*)&As[buf][0] + (size_t)s*16);
      gload_lds16(bsrc[i], (char*)&Bs[buf][0] + (size_t)s*16);
      asrc[i] += 32; bsrc[i] += 32;
    }
  };
  // fragment read byte-offsets within a buffer (hi; lo = ^64)
  int aoh[4], boh[4];
  #pragma unroll
  for (int f = 0; f < 4; ++f) {
    aoh[f] = (wm + f*16 + lr)*128 + ((lg ^ lr7)*16);
    boh[f] = (wn + f*16 + lr)*128 + ((lg ^ lr7)*16);
  }

  f32x4 zero = {0.f, 0.f, 0.f, 0.f};
  f32x4 acc[4][4];
  #pragma unroll
  for (int i = 0; i < 4; ++i)
    #pragma unroll
    for (int j = 0; j < 4; ++j) acc[i][j] = zero;

  stage(0);
  __syncthreads();                           // prologue: full drain once
  int cur = 0;
  int nk = K >> 5;
  for (int t = 0; t < nk; ++t) {
    if (t + 1 < nk) stage(cur ^ 1);          // prefetch next K-tile (no wait)
    const char* AB = (const char*)&As[cur][0];
    const char* BB = (const char*)&Bs[cur][0];
    short8 ahf[4], alf[4];
    #pragma unroll
    for (int mf = 0; mf < 4; ++mf) {
      ahf[mf] = *(const short8*)(AB + aoh[mf]);
      alf[mf] = *(const short8*)(AB + (aoh[mf] ^ 64));
    }
    #pragma unroll
    for (int nf = 0; nf < 4; ++nf) {
      short8 bhf = *(const short8*)(BB + boh[nf]);
      short8 blf = *(const short8*)(BB + (boh[nf] ^ 64));
      #pragma unroll
      for (int mf = 0; mf < 4; ++mf) {
        acc[mf][nf] = mfma16(ahf[mf], bhf, acc[mf][nf]);
        acc[mf][nf] = mfma16(ahf[mf], blf, acc[mf][nf]);
        acc[mf][nf] = mfma16(alf[mf], bhf, acc[mf][nf]);
      }
    }
    barrier_inflight8();                     // wait prev tile only; keep prefetch in flight
    cur ^= 1;
  }
  // epilogue: D row = lg*4+r, col = lr (m89 layout)
  #pragma unroll
  for (int nf = 0; nf < 4; ++nf) {
    int col = bn + wn + nf*16 + lr;
    float bv = bias[col];
    #pragma unroll
    for (int mf = 0; mf < 4; ++mf) {
      #pragma unroll
      for (int r = 0; r < 4; ++r) {
        int rowm = bm + wm + mf*16 + lg*4 + r;
        float v = acc[mf][nf][r] + bv;
        if (MODE == 1) {
          fout[(size_t)rowm*N + col] = v;
        } else {
          int sec = col >> 10;          // 0=q 1=k 2=v
          int hh  = (col >> 6) & 15;
          int d   = col & 63;
          int b   = rowm >> 11, t = rowm & 2047;
          size_t bhh = (size_t)b*NH + hh;
          if (sec == 0) v *= 0.125f;    // fold 1/sqrt(HD) into Q
          uint32_t bt = __float_as_uint(v);
          unsigned short h16 = (unsigned short)(bt >> 16);
          unsigned short l16 = rne16(v - __uint_as_float(bt & 0xffff0000u));
          if (sec == 0)      { size_t o = (bhh*T_ + t)*HD + d;  qh[o] = h16;  ql[o] = l16; }
          else if (sec == 1) { size_t o = (bhh*T_ + t)*HD + d;  kh[o] = h16;  kl[o] = l16; }
          else               { size_t o = (bhh*HD + d)*T_ + t;  vth[o] = h16; vtl[o] = l16; }
        }
      }
    }
  }
}

// ---------------- flash attention (causal), swapped-operand form ----------------
// As R4 (4 waves x 16 q rows, KV tiles 32, dbuf) but with the counted-vmcnt
// barrier (vmcnt(4): one stage = 2 K + 2 V gload_lds per thread).

__global__ __launch_bounds__(256, 4) void attn_kernel(
    const unsigned short* __restrict__ qh, const unsigned short* __restrict__ ql,
    const unsigned short* __restrict__ kh, const unsigned short* __restrict__ kl,
    const unsigned short* __restrict__ vth, const unsigned short* __restrict__ vtl,
    unsigned short* __restrict__ ctxh, unsigned short* __restrict__ ctxl) {
  __shared__ unsigned short Kt[2][32*128];  // 32 kv-rows x (hi128B|lo128B) = 8KB each
  __shared__ unsigned short Vt[2][64*64];   // 64 d-rows x (hi64B|lo64B)   = 8KB each
  int b = blockIdx.x;
  int xcd = b & 7, bh_lo = (b >> 3) & 3, jj = (b >> 5) & 7, kk = b >> 8;
  int bh = xcd*4 + bh_lo;
  int qt = (kk == 0) ? jj : (kk == 1) ? 15 - jj : (kk == 2) ? 16 + jj : 31 - jj;
  int q0 = qt * 64;
  int tid = threadIdx.x;
  int w = tid >> 6, l = tid & 63, lg = l >> 4, lr = l & 15;
  int q0w = q0 + w*16;
  int qrow = q0w + lr;

  // Q B-frags (col=q=lr, k=d=lg*8+j+32ks); Q pre-scaled by 0.125
  const unsigned short* qbh = qh + ((size_t)bh*T_ + qrow)*HD;
  const unsigned short* qbl = ql + ((size_t)bh*T_ + qrow)*HD;
  short8 qfh[2], qfl[2];
  #pragma unroll
  for (int ks = 0; ks < 2; ++ks) {
    qfh[ks] = *(const short8*)(qbh + ks*32 + lg*8);
    qfl[ks] = *(const short8*)(qbl + ks*32 + lg*8);
  }

  // staging sources: K 512 slots (32 rows x 16 gran), V 512 slots (64 rows x 8 gran)
  const unsigned short* ksrc[2]; const unsigned short* vsrc[2];
  #pragma unroll
  for (int i = 0; i < 2; ++i) {
    int s = tid + 256*i;
    { int r = s >> 4, p = s & 15, u = (p & 8) | ((p & 7) ^ (r & 7));
      ksrc[i] = ((u < 8) ? kh : kl) + ((size_t)bh*T_ + r)*HD + (u & 7)*8; }
    { int r = s >> 3, p = s & 7, u = p ^ (r & 7);
      vsrc[i] = ((u < 4) ? vth : vtl) + ((size_t)bh*HD + r)*T_ + (u & 3)*8; }
  }
  auto stage = [&](int buf) {
    #pragma unroll
    for (int i = 0; i < 2; ++i) {
      int s = tid + 256*i;
      gload_lds16(ksrc[i], (char*)&Kt[buf][0] + (size_t)s*16);
      gload_lds16(vsrc[i], (char*)&Vt[buf][0] + (size_t)s*16);
      ksrc[i] += 32*HD;     // next 32 kv rows
      vsrc[i] += 32;        // next 32 kv cols
    }
  };

  // K A-frag offsets: row=kv=fc*16+lr, k=d=ks*32+lg*8+j ; lo = +128
  int koff[2][2];
  #pragma unroll
  for (int fc = 0; fc < 2; ++fc)
    #pragma unroll
    for (int ks = 0; ks < 2; ++ks) {
      int row = fc*16 + lr;
      koff[fc][ks] = row*256 + (((ks*4 + lg) ^ (row & 7))*16);
    }
  // V A-frag offsets: row=d=df*16+lr, k=kv=lg*8+j ; lo = ^64
  int voff[4];
  #pragma unroll
  for (int df = 0; df < 4; ++df) {
    int row = df*16 + lr;
    voff[df] = row*128 + ((lg ^ (row & 7))*16);
  }

  f32x4 zero = {0.f, 0.f, 0.f, 0.f};
  f32x4 o[4] = {zero, zero, zero, zero};
  float m_r = -1e30f, l_r = 0.f;

  int nkt = 2*qt + 2;
  stage(0);
  __syncthreads();                           // prologue: full drain once
  int cur = 0;

  // shfl source lanes for P^T redistribution
  int sl = lr + ((lg & 1) << 5);
  int sh = sl + 16;
  bool lglo = lg < 2;

  for (int kt = 0; kt < nkt; ++kt) {
    int kv0 = kt*32;
    if (kt + 1 < nkt) stage(cur ^ 1);
    if (kv0 <= q0w + 15) {                    // wave has live rows in this tile
      const char* KB = (const char*)&Kt[cur][0];
      const char* VB = (const char*)&Vt[cur][0];
      // S^T = K * Q^T   (lane: q=qrow, kv=kv0+fc*16+lg*4+r)
      f32x4 st[2];
      #pragma unroll
      for (int fc = 0; fc < 2; ++fc) {
        f32x4 acc = zero;
        #pragma unroll
        for (int ks = 0; ks < 2; ++ks) {
          short8 khf = *(const short8*)(KB + koff[fc][ks]);
          short8 klf = *(const short8*)(KB + koff[fc][ks] + 128);
          acc = mfma16(khf, qfh[ks], acc);
          acc = mfma16(khf, qfl[ks], acc);
          acc = mfma16(klf, qfh[ks], acc);
        }
        st[fc] = acc;
      }
      if (kv0 + 31 > q0w) {                   // diagonal: elementwise causal mask
        #pragma unroll
        for (int fc = 0; fc < 2; ++fc)
          #pragma unroll
          for (int r = 0; r < 4; ++r) {
            int kv = kv0 + fc*16 + lg*4 + r;
            if (kv > qrow) st[fc][r] = -1e30f;
          }
      }
      // online softmax: per-lane scalar row state
      float pm = fmaxf(fmaxf(fmaxf(st[0][0], st[0][1]), fmaxf(st[0][2], st[0][3])),
                       fmaxf(fmaxf(st[1][0], st[1][1]), fmaxf(st[1][2], st[1][3])));
      pm = fmaxf(pm, __shfl_xor(pm, 16));
      pm = fmaxf(pm, __shfl_xor(pm, 32));
      if (__any(pm > m_r + 8.f)) {            // defer-max (THR=8)
        float mn = fmaxf(m_r, pm);
        float sc = __expf(m_r - mn);
        m_r = mn; l_r *= sc;
        #pragma unroll
        for (int df = 0; df < 4; ++df)
          #pragma unroll
          for (int r = 0; r < 4; ++r) o[df][r] *= sc;
      }
      float sum = 0.f;
      #pragma unroll
      for (int fc = 0; fc < 2; ++fc)
        #pragma unroll
        for (int r = 0; r < 4; ++r) {
          float p = __expf(st[fc][r] - m_r);
          st[fc][r] = p;
          sum += p;
        }
      sum += __shfl_xor(sum, 16);
      sum += __shfl_xor(sum, 32);
      l_r += sum;
      // pack P pairs (hi RNE, lo residual)
      uint32_t Hpk[2][2], Lpk[2][2];
      #pragma unroll
      for (int fc = 0; fc < 2; ++fc)
        #pragma unroll
        for (int i = 0; i < 2; ++i) {
          float pe = st[fc][2*i], po = st[fc][2*i + 1];
          uint32_t H = cvtpk_bf16(pe, po);
          Hpk[fc][i] = H;
          float fe = __uint_as_float(H << 16);
          float fo = __uint_as_float(H & 0xffff0000u);
          Lpk[fc][i] = cvtpk_bf16(pe - fe, po - fo);
        }
      // redistribute to PV B-operand layout (col=q=lr, k=kv=lg*8+j)
      union { u32x4 u; short8 s; } BH, BL;
      {
        int a0 = __shfl((int)Hpk[0][0], sl), b0 = __shfl((int)Hpk[1][0], sl);
        int a1 = __shfl((int)Hpk[0][1], sl), b1 = __shfl((int)Hpk[1][1], sl);
        int a2 = __shfl((int)Hpk[0][0], sh), b2 = __shfl((int)Hpk[1][0], sh);
        int a3 = __shfl((int)Hpk[0][1], sh), b3 = __shfl((int)Hpk[1][1], sh);
        BH.u[0] = lglo ? a0 : b0; BH.u[1] = lglo ? a1 : b1;
        BH.u[2] = lglo ? a2 : b2; BH.u[3] = lglo ? a3 : b3;
      }
      {
        int a0 = __shfl((int)Lpk[0][0], sl), b0 = __shfl((int)Lpk[1][0], sl);
        int a1 = __shfl((int)Lpk[0][1], sl), b1 = __shfl((int)Lpk[1][1], sl);
        int a2 = __shfl((int)Lpk[0][0], sh), b2 = __shfl((int)Lpk[1][0], sh);
        int a3 = __shfl((int)Lpk[0][1], sh), b3 = __shfl((int)Lpk[1][1], sh);
        BL.u[0] = lglo ? a0 : b0; BL.u[1] = lglo ? a1 : b1;
        BL.u[2] = lglo ? a2 : b2; BL.u[3] = lglo ? a3 : b3;
      }
      // O^T += V^T * P^T
      #pragma unroll
      for (int df = 0; df < 4; ++df) {
        short8 vhf = *(const short8*)(VB + voff[df]);
        short8 vlf = *(const short8*)(VB + (voff[df] ^ 64));
        o[df] = mfma16(vhf, BH.s, o[df]);
        o[df] = mfma16(vhf, BL.s, o[df]);
        o[df] = mfma16(vlf, BH.s, o[df]);
      }
    }
    barrier_inflight4();                      // keep prefetch in flight
    cur ^= 1;
  }
  // epilogue: lane holds O[q=qrow][d=df*16+lg*4+r]; ctx planes [b][t][h*64+d]
  int bb = bh >> 4, h = bh & 15;
  float inv = 1.0f / l_r;
  #pragma unroll
  for (int df = 0; df < 4; ++df) {
    ushort4 hv, lv;
    unsigned short hh[4], ll[4];
    #pragma unroll
    for (int r = 0; r < 4; ++r) {
      float v = o[df][r] * inv;
      uint32_t bt = __float_as_uint(v);
      hh[r] = (unsigned short)(bt >> 16);
      ll[r] = rne16(v - __uint_as_float(bt & 0xffff0000u));
    }
    hv.x=hh[0]; hv.y=hh[1]; hv.z=hh[2]; hv.w=hh[3];
    lv.x=ll[0]; lv.y=ll[1]; lv.z=ll[2]; lv.w=ll[3];
    size_t oo = ((size_t)bb*T_ + qrow)*C_ + h*HD + df*16 + lg*4;
    *(ushort4*)&ctxh[oo] = hv;
    *(ushort4*)&ctxl[oo] = lv;
  }
}

// ---------------- launch ----------------

extern "C" void kernel_launch(void* const* d_in, const int* in_sizes, int n_in,
                              void* d_out, int out_size, void* d_ws, size_t ws_size,
                              hipStream_t stream) {
  (void)in_sizes; (void)n_in; (void)out_size; (void)ws_size;
  const float* x      = (const float*)d_in[0];
  const float* w_qkv  = (const float*)d_in[1];
  const float* b_qkv  = (const float*)d_in[2];
  const float* w_proj = (const float*)d_in[3];
  const float* b_proj = (const float*)d_in[4];
  float* out = (float*)d_out;

  uint8_t* ws = (uint8_t*)d_ws;
  const size_t MB = (size_t)1 << 20;
  unsigned short* xh  = (unsigned short*)(ws + 0);      // 8MB  [M][C] hi
  unsigned short* xl  = (unsigned short*)(ws + 8*MB);   // 8MB  lo
  unsigned short* cth = xh;                             // ctx aliases x (dead)
  unsigned short* ctl = xl;
  unsigned short* wqh = (unsigned short*)(ws + 16*MB);  // 6MB  w_qkv^T hi [3C][C]
  unsigned short* wql = (unsigned short*)(ws + 22*MB);  // 6MB
  unsigned short* wph = (unsigned short*)(ws + 28*MB);  // 2MB  w_proj^T hi [C][C]
  unsigned short* wpl = (unsigned short*)(ws + 30*MB);  // 2MB
  unsigned short* qhp = (unsigned short*)(ws + 32*MB);  // 8MB  Q hi [BH][T][HD] (x0.125)
  unsigned short* qlp = (unsigned short*)(ws + 40*MB);  // 8MB
  unsigned short* khp = (unsigned short*)(ws + 48*MB);  // 8MB  K hi
  unsigned short* klp = (unsigned short*)(ws + 56*MB);  // 8MB
  unsigned short* vth = (unsigned short*)(ws + 64*MB);  // 8MB  V^T hi [BH][HD][T]
  unsigned short* vtl = (unsigned short*)(ws + 72*MB);  // 8MB   -> 80MB total

  pack4_kernel<<<(M_*C_/4 + 255)/256, 256, 0, stream>>>((const float4*)x, xh, xl, M_*C_/4);
  pack_t_kernel<<<dim3(3*C_/64, C_/64), dim3(64, 16), 0, stream>>>(w_qkv, wqh, wql, C_, 3*C_);
  pack_t_kernel<<<dim3(C_/64, C_/64), dim3(64, 16), 0, stream>>>(w_proj, wph, wpl, C_, C_);
  gemm_planes<0><<<dim3(3*C_/128, M_/128), 256, 0, stream>>>(
      xh, xl, wqh, wql, b_qkv, qhp, qlp, khp, klp, vth, vtl, nullptr, M_, 3*C_, C_);
  attn_kernel<<<dim3(1024), 256, 0, stream>>>(qhp, qlp, khp, klp, vth, vtl, cth, ctl);
  gemm_planes<1><<<dim3(C_/128, M_/128), 256, 0, stream>>>(
      cth, ctl, wph, wpl, b_proj, nullptr, nullptr, nullptr, nullptr, nullptr, nullptr,
      out, M_, C_, C_);
}